// Round 1
// baseline (937.401 us; speedup 1.0000x reference)
//
#include <hip/hip_runtime.h>
#include <hip/hip_bf16.h>

// InteractionNetworkLayer on MI355X — round 1 (correctness-first bf16 MFMA).
//
// Structure:
//   prep_weights : f32 W -> bf16 W^T  (k-contiguous rows for MFMA frags)
//   prep_nodes   : f32 nodes -> bf16 nodes  (gathered by edge kernel)
//   memset agg
//   edge_kernel  : per 64-edge tile: h^T = relu(W1^T . edge_in^T + b1) via MFMA
//                  (edge_in gathered as per-lane global frags, never materialized),
//                  h^T -> swizzled LDS, edges_new^T = W2^T . h^T + b2,
//                  edges_out = edges + edges_new, atomicAdd into agg[recv].
//   node_kernel  : same for nodes with A = [agg | nodes], nodes_out = nodes + new.
//
// MFMA 16x16x32 bf16; both operands loaded with identical per-lane
// k-contiguous-8 mapping => any internal k-permutation cancels.
// C/D layout (verified): col = lane&15, row = (lane>>4)*4 + reg.

typedef __attribute__((ext_vector_type(8))) short bf16x8;
typedef __attribute__((ext_vector_type(4))) float f32x4;
typedef unsigned long long u64;
typedef unsigned short u16;
typedef unsigned int u32;

#define BATCH 2
#define NN 16384
#define NE 131072
#define DN 256
#define DE 128

// ws byte offsets
#define WS_EW1T   0u          // 640x256 bf16 = 327680 B
#define WS_EW2T   327680u     // 256x128 bf16 = 65536 B
#define WS_NW1T   393216u     // 384x256 bf16 = 196608 B
#define WS_NW2T   589824u     // 256x256 bf16 = 131072 B
#define WS_NODESBF 720896u    // 2*16384*256 bf16 = 16777216 B
#define WS_AGG    17498112u   // 2*16384*128 f32 = 16777216 B

// u16-unit offsets inside the weight block
#define O_EW1T 0
#define O_EW2T 163840
#define O_NW1T 196608
#define O_NW2T 294912

__device__ inline u16 f2bf(float f) {
  u32 u = __builtin_bit_cast(u32, f);
  u32 r = u + 0x7FFFu + ((u >> 16) & 1u);
  return (u16)(r >> 16);
}

__device__ inline u64 pack4bf(f32x4 v) {
  return (u64)f2bf(v[0]) | ((u64)f2bf(v[1]) << 16) |
         ((u64)f2bf(v[2]) << 32) | ((u64)f2bf(v[3]) << 48);
}

__device__ inline bf16x8 load8f_bf(const float* __restrict__ p) {
  f32x4 a = *(const f32x4*)p;
  f32x4 c = *(const f32x4*)(p + 4);
  bf16x8 r;
  r[0] = (short)f2bf(a[0]); r[1] = (short)f2bf(a[1]);
  r[2] = (short)f2bf(a[2]); r[3] = (short)f2bf(a[3]);
  r[4] = (short)f2bf(c[0]); r[5] = (short)f2bf(c[1]);
  r[6] = (short)f2bf(c[2]); r[7] = (short)f2bf(c[3]);
  return r;
}

__global__ void prep_weights(const float* __restrict__ eW1, const float* __restrict__ eW2,
                             const float* __restrict__ nW1, const float* __restrict__ nW2,
                             u16* __restrict__ wb) {
  int o = blockIdx.x * 256 + threadIdx.x;
  if (o < 163840) {                       // eW1T[n][k], n<256,k<640
    int n = o / 640, k = o % 640;
    wb[O_EW1T + o] = f2bf(eW1[k * 256 + n]);
  } else if (o < 196608) {                // eW2T[n][k], n<128,k<256
    int o2 = o - 163840; int n = o2 >> 8, k = o2 & 255;
    wb[O_EW2T + o2] = f2bf(eW2[k * 128 + n]);
  } else if (o < 294912) {                // nW1T[n][k], n<256,k<384
    int o3 = o - 196608; int n = o3 / 384, k = o3 % 384;
    wb[O_NW1T + o3] = f2bf(nW1[k * 256 + n]);
  } else if (o < 360448) {                // nW2T[n][k], n<256,k<256
    int o4 = o - 294912; int n = o4 >> 8, k = o4 & 255;
    wb[O_NW2T + o4] = f2bf(nW2[k * 256 + n]);
  }
}

__global__ void prep_nodes(const float* __restrict__ nodes, u64* __restrict__ nbf) {
  const size_t total = (size_t)BATCH * NN * DN / 4;  // 2097152 groups of 4
  for (size_t i = (size_t)blockIdx.x * 256 + threadIdx.x; i < total;
       i += (size_t)gridDim.x * 256) {
    f32x4 v = ((const f32x4*)nodes)[i];
    nbf[i] = pack4bf(v);
  }
}

__global__ __launch_bounds__(256) void edge_kernel(
    const float* __restrict__ edges,
    const int* __restrict__ senders, const int* __restrict__ receivers,
    const float* __restrict__ eb1, const float* __restrict__ eb2,
    const u16* __restrict__ eW1T, const u16* __restrict__ eW2T,
    const u16* __restrict__ nodesbf, float* __restrict__ agg,
    float* __restrict__ out_edges) {
  __shared__ u64 hT[4096];  // [64 e][64 slots of 4 bf16], slot XOR-swizzled by e&7

  const int t = threadIdx.x;
  const int lane = t & 63;
  const int wv = t >> 6;        // wave 0..3
  const int lg = lane >> 4;     // lane group 0..3
  const int lr = lane & 15;     // lane row/col 0..15
  const int b = blockIdx.x >> 11;                 // 2048 blocks per batch
  const int e0 = (blockIdx.x << 6) & (NE - 1);    // edge base in batch

  int r_ef[4], s_ef[4];
#pragma unroll
  for (int ef = 0; ef < 4; ++ef) {
    int e = e0 + ef * 16 + lr;
    r_ef[ef] = receivers[(size_t)b * NE + e];
    s_ef[ef] = senders[(size_t)b * NE + e];
  }

  const u16* __restrict__ nbf = nodesbf + (size_t)b * NN * DN;
  const int nb = wv * 64;  // this wave's hidden-row base

  f32x4 acc1[4][4];
#pragma unroll
  for (int i = 0; i < 4; ++i)
#pragma unroll
    for (int j = 0; j < 4; ++j) acc1[i][j] = (f32x4){0.f, 0.f, 0.f, 0.f};

  // ---- GEMM1: h^T[n][e] over K = 640 (recv 0..255 | send 256..511 | edges 512..639)
#pragma unroll 2
  for (int kt = 0; kt < 10; ++kt) {
#pragma unroll
    for (int kf = 0; kf < 2; ++kf) {
      const int k = kt * 64 + kf * 32 + lg * 8;
      bf16x8 xf[4];
#pragma unroll
      for (int nf = 0; nf < 4; ++nf)
        xf[nf] = *(const bf16x8*)(eW1T + (size_t)(nb + nf * 16 + lr) * 640 + k);
      bf16x8 yf[4];
      if (kt < 4) {
#pragma unroll
        for (int ef = 0; ef < 4; ++ef)
          yf[ef] = *(const bf16x8*)(nbf + (size_t)r_ef[ef] * DN + k);
      } else if (kt < 8) {
#pragma unroll
        for (int ef = 0; ef < 4; ++ef)
          yf[ef] = *(const bf16x8*)(nbf + (size_t)s_ef[ef] * DN + (k - 256));
      } else {
#pragma unroll
        for (int ef = 0; ef < 4; ++ef)
          yf[ef] = load8f_bf(edges + ((size_t)b * NE + e0 + ef * 16 + lr) * DE + (k - 512));
      }
#pragma unroll
      for (int nf = 0; nf < 4; ++nf)
#pragma unroll
        for (int ef = 0; ef < 4; ++ef)
          acc1[nf][ef] = __builtin_amdgcn_mfma_f32_16x16x32_bf16(
              xf[nf], yf[ef], acc1[nf][ef], 0, 0, 0);
    }
  }

  // ---- epilogue 1: bias + relu, pack to bf16, write h^T to LDS
#pragma unroll
  for (int nf = 0; nf < 4; ++nf) {
    f32x4 bias = *(const f32x4*)(eb1 + nb + nf * 16 + lg * 4);
#pragma unroll
    for (int ef = 0; ef < 4; ++ef) {
      f32x4 v = acc1[nf][ef] + bias;
#pragma unroll
      for (int j = 0; j < 4; ++j) v[j] = v[j] > 0.f ? v[j] : 0.f;
      int e = ef * 16 + lr;
      int s = 16 * wv + nf * 4 + lg;   // slot = n/4
      hT[e * 64 + (s ^ (e & 7))] = pack4bf(v);
    }
  }
  __syncthreads();

  // ---- GEMM2: edges_new^T[o][e] = W2^T . h^T, K = 256
  f32x4 acc2[2][4];
#pragma unroll
  for (int i = 0; i < 2; ++i)
#pragma unroll
    for (int j = 0; j < 4; ++j) acc2[i][j] = (f32x4){0.f, 0.f, 0.f, 0.f};

#pragma unroll 2
  for (int kf = 0; kf < 8; ++kf) {
    bf16x8 x2[2];
#pragma unroll
    for (int of = 0; of < 2; ++of)
      x2[of] = *(const bf16x8*)(eW2T + (size_t)(32 * wv + of * 16 + lr) * 256 + kf * 32 + lg * 8);
    bf16x8 y2[4];
#pragma unroll
    for (int ef = 0; ef < 4; ++ef) {
      int e = ef * 16 + lr;
      int s0 = kf * 8 + lg * 2;
      union { u64 q[2]; bf16x8 v; } uu;
      uu.q[0] = hT[e * 64 + (s0 ^ (e & 7))];
      uu.q[1] = hT[e * 64 + ((s0 + 1) ^ (e & 7))];
      y2[ef] = uu.v;
    }
#pragma unroll
    for (int of = 0; of < 2; ++of)
#pragma unroll
      for (int ef = 0; ef < 4; ++ef)
        acc2[of][ef] = __builtin_amdgcn_mfma_f32_16x16x32_bf16(
            x2[of], y2[ef], acc2[of][ef], 0, 0, 0);
  }

  // ---- epilogue 2: bias, residual edges_out, atomic scatter into agg
#pragma unroll
  for (int of = 0; of < 2; ++of) {
    const int obase = 32 * wv + of * 16 + lg * 4;
    f32x4 b2 = *(const f32x4*)(eb2 + obase);
#pragma unroll
    for (int ef = 0; ef < 4; ++ef) {
      f32x4 en = acc2[of][ef] + b2;  // edges_new
      size_t erow = (size_t)b * NE + e0 + ef * 16 + lr;
      f32x4 eold = *(const f32x4*)(edges + erow * DE + obase);
      *(f32x4*)(out_edges + erow * DE + obase) = eold + en;
      float* ap = agg + ((size_t)b * NN + r_ef[ef]) * DE + obase;
      atomicAdd(ap + 0, en[0]);
      atomicAdd(ap + 1, en[1]);
      atomicAdd(ap + 2, en[2]);
      atomicAdd(ap + 3, en[3]);
    }
  }
}

__global__ __launch_bounds__(256) void node_kernel(
    const float* __restrict__ nodes,
    const float* __restrict__ nb1, const float* __restrict__ nb2,
    const u16* __restrict__ nW1T, const u16* __restrict__ nW2T,
    const u16* __restrict__ nodesbf, const float* __restrict__ agg,
    float* __restrict__ out_nodes) {
  __shared__ u64 hT[4096];

  const int t = threadIdx.x;
  const int lane = t & 63;
  const int wv = t >> 6;
  const int lg = lane >> 4;
  const int lr = lane & 15;
  const int b = blockIdx.x >> 8;                  // 256 blocks per batch
  const int m0 = (blockIdx.x << 6) & (NN - 1);

  const u16* __restrict__ nbf = nodesbf + (size_t)b * NN * DN;
  const float* __restrict__ aggb = agg + (size_t)b * NN * DE;
  const int nb = wv * 64;

  f32x4 acc1[4][4];
#pragma unroll
  for (int i = 0; i < 4; ++i)
#pragma unroll
    for (int j = 0; j < 4; ++j) acc1[i][j] = (f32x4){0.f, 0.f, 0.f, 0.f};

  // ---- GEMM1: h2^T over K = 384 (agg 0..127 | nodes 128..383)
#pragma unroll 2
  for (int kt = 0; kt < 6; ++kt) {
#pragma unroll
    for (int kf = 0; kf < 2; ++kf) {
      const int k = kt * 64 + kf * 32 + lg * 8;
      bf16x8 xf[4];
#pragma unroll
      for (int nf = 0; nf < 4; ++nf)
        xf[nf] = *(const bf16x8*)(nW1T + (size_t)(nb + nf * 16 + lr) * 384 + k);
      bf16x8 yf[4];
      if (kt < 2) {
#pragma unroll
        for (int ef = 0; ef < 4; ++ef)
          yf[ef] = load8f_bf(aggb + (size_t)(m0 + ef * 16 + lr) * DE + k);
      } else {
#pragma unroll
        for (int ef = 0; ef < 4; ++ef)
          yf[ef] = *(const bf16x8*)(nbf + (size_t)(m0 + ef * 16 + lr) * DN + (k - 128));
      }
#pragma unroll
      for (int nf = 0; nf < 4; ++nf)
#pragma unroll
        for (int ef = 0; ef < 4; ++ef)
          acc1[nf][ef] = __builtin_amdgcn_mfma_f32_16x16x32_bf16(
              xf[nf], yf[ef], acc1[nf][ef], 0, 0, 0);
    }
  }

  // ---- epilogue 1
#pragma unroll
  for (int nf = 0; nf < 4; ++nf) {
    f32x4 bias = *(const f32x4*)(nb1 + nb + nf * 16 + lg * 4);
#pragma unroll
    for (int ef = 0; ef < 4; ++ef) {
      f32x4 v = acc1[nf][ef] + bias;
#pragma unroll
      for (int j = 0; j < 4; ++j) v[j] = v[j] > 0.f ? v[j] : 0.f;
      int e = ef * 16 + lr;
      int s = 16 * wv + nf * 4 + lg;
      hT[e * 64 + (s ^ (e & 7))] = pack4bf(v);
    }
  }
  __syncthreads();

  // ---- GEMM2: nodes_new^T[o][m], o range 64 per wave, K = 256
  f32x4 acc2[4][4];
#pragma unroll
  for (int i = 0; i < 4; ++i)
#pragma unroll
    for (int j = 0; j < 4; ++j) acc2[i][j] = (f32x4){0.f, 0.f, 0.f, 0.f};

#pragma unroll 2
  for (int kf = 0; kf < 8; ++kf) {
    bf16x8 x2[4];
#pragma unroll
    for (int of = 0; of < 4; ++of)
      x2[of] = *(const bf16x8*)(nW2T + (size_t)(64 * wv + of * 16 + lr) * 256 + kf * 32 + lg * 8);
    bf16x8 y2[4];
#pragma unroll
    for (int ef = 0; ef < 4; ++ef) {
      int e = ef * 16 + lr;
      int s0 = kf * 8 + lg * 2;
      union { u64 q[2]; bf16x8 v; } uu;
      uu.q[0] = hT[e * 64 + (s0 ^ (e & 7))];
      uu.q[1] = hT[e * 64 + ((s0 + 1) ^ (e & 7))];
      y2[ef] = uu.v;
    }
#pragma unroll
    for (int of = 0; of < 4; ++of)
#pragma unroll
      for (int ef = 0; ef < 4; ++ef)
        acc2[of][ef] = __builtin_amdgcn_mfma_f32_16x16x32_bf16(
            x2[of], y2[ef], acc2[of][ef], 0, 0, 0);
  }

  // ---- epilogue 2: bias + residual
#pragma unroll
  for (int of = 0; of < 4; ++of) {
    const int obase = 64 * wv + of * 16 + lg * 4;
    f32x4 b2 = *(const f32x4*)(nb2 + obase);
#pragma unroll
    for (int ef = 0; ef < 4; ++ef) {
      f32x4 nn = acc2[of][ef] + b2;
      size_t mrow = (size_t)b * NN + m0 + ef * 16 + lr;
      f32x4 nold = *(const f32x4*)(nodes + mrow * DN + obase);
      *(f32x4*)(out_nodes + mrow * DN + obase) = nold + nn;
    }
  }
}

extern "C" void kernel_launch(void* const* d_in, const int* in_sizes, int n_in,
                              void* d_out, int out_size, void* d_ws, size_t ws_size,
                              hipStream_t stream) {
  const float* nodes = (const float*)d_in[0];
  const float* edges = (const float*)d_in[1];
  const int* senders = (const int*)d_in[2];
  const int* receivers = (const int*)d_in[3];
  const float* eW1 = (const float*)d_in[4];
  const float* eb1 = (const float*)d_in[5];
  const float* eW2 = (const float*)d_in[6];
  const float* eb2 = (const float*)d_in[7];
  const float* nW1 = (const float*)d_in[8];
  const float* nb1 = (const float*)d_in[9];
  const float* nW2 = (const float*)d_in[10];
  const float* nb2 = (const float*)d_in[11];

  char* ws = (char*)d_ws;
  u16* wb = (u16*)(ws + WS_EW1T);
  u16* nodesbf = (u16*)(ws + WS_NODESBF);
  float* agg = (float*)(ws + WS_AGG);
  float* out = (float*)d_out;

  hipMemsetAsync(agg, 0, (size_t)BATCH * NN * DE * sizeof(float), stream);
  prep_weights<<<1408, 256, 0, stream>>>(eW1, eW2, nW1, nW2, wb);
  prep_nodes<<<2048, 256, 0, stream>>>(nodes, (u64*)nodesbf);
  edge_kernel<<<4096, 256, 0, stream>>>(edges, senders, receivers, eb1, eb2,
                                        wb + O_EW1T, wb + O_EW2T, nodesbf, agg,
                                        out + (size_t)BATCH * NN * DN);
  node_kernel<<<512, 256, 0, stream>>>(nodes, nb1, nb2, wb + O_NW1T, wb + O_NW2T,
                                       nodesbf, agg, out);
  (void)in_sizes; (void)n_in; (void)out_size; (void)ws_size;
}

// Round 2
// 872.780 us; speedup vs baseline: 1.0740x; 1.0740x over previous
//
#include <hip/hip_runtime.h>
#include <hip/hip_bf16.h>

// InteractionNetworkLayer on MI355X — round 2: LDS-staged gathers.
//
// Round-1 diagnosis: edge_kernel latency-bound (MfmaUtil 6%, HBM 17%).
// Fix: bulk-stage recv/send node rows into LDS with coalesced loads
// (2 full 512B rows per wave-instruction) + XOR-swizzled 16B slots, so the
// GEMM1 inner loop reads operands from LDS instead of chasing random global
// rows. hT overlays the recv region after GEMM1 (LDS = 64KB, 2 blocks/CU).
// Also: agg converted to bf16 before node_kernel (halves its gather bytes,
// drops f32->bf16 VALU work from its hot loop).

typedef __attribute__((ext_vector_type(8))) short bf16x8;
typedef __attribute__((ext_vector_type(4))) float f32x4;
typedef unsigned long long u64;
typedef unsigned short u16;
typedef unsigned int u32;

#define BATCH 2
#define NN 16384
#define NE 131072
#define DN 256
#define DE 128

// ws byte offsets
#define WS_EW1T   0u          // 640x256 bf16 = 327680 B
#define WS_EW2T   327680u     // 256x128 bf16 = 65536 B
#define WS_NW1T   393216u     // 384x256 bf16 = 196608 B
#define WS_NW2T   589824u     // 256x256 bf16 = 131072 B
#define WS_NODESBF 720896u    // 2*16384*256 bf16 = 16777216 B
#define WS_AGG    17498112u   // 2*16384*128 f32 = 16777216 B
#define WS_AGGBF  34275328u   // 2*16384*128 bf16 = 8388608 B

// u16-unit offsets inside the weight block
#define O_EW1T 0
#define O_EW2T 163840
#define O_NW1T 196608
#define O_NW2T 294912

__device__ inline u16 f2bf(float f) {
  u32 u = __builtin_bit_cast(u32, f);
  u32 r = u + 0x7FFFu + ((u >> 16) & 1u);
  return (u16)(r >> 16);
}

__device__ inline u64 pack4bf(f32x4 v) {
  return (u64)f2bf(v[0]) | ((u64)f2bf(v[1]) << 16) |
         ((u64)f2bf(v[2]) << 32) | ((u64)f2bf(v[3]) << 48);
}

__device__ inline bf16x8 load8f_bf(const float* __restrict__ p) {
  f32x4 a = *(const f32x4*)p;
  f32x4 c = *(const f32x4*)(p + 4);
  bf16x8 r;
  r[0] = (short)f2bf(a[0]); r[1] = (short)f2bf(a[1]);
  r[2] = (short)f2bf(a[2]); r[3] = (short)f2bf(a[3]);
  r[4] = (short)f2bf(c[0]); r[5] = (short)f2bf(c[1]);
  r[6] = (short)f2bf(c[2]); r[7] = (short)f2bf(c[3]);
  return r;
}

__global__ void prep_weights(const float* __restrict__ eW1, const float* __restrict__ eW2,
                             const float* __restrict__ nW1, const float* __restrict__ nW2,
                             u16* __restrict__ wb) {
  int o = blockIdx.x * 256 + threadIdx.x;
  if (o < 163840) {                       // eW1T[n][k], n<256,k<640
    int n = o / 640, k = o % 640;
    wb[O_EW1T + o] = f2bf(eW1[k * 256 + n]);
  } else if (o < 196608) {                // eW2T[n][k], n<128,k<256
    int o2 = o - 163840; int n = o2 >> 8, k = o2 & 255;
    wb[O_EW2T + o2] = f2bf(eW2[k * 128 + n]);
  } else if (o < 294912) {                // nW1T[n][k], n<256,k<384
    int o3 = o - 196608; int n = o3 / 384, k = o3 % 384;
    wb[O_NW1T + o3] = f2bf(nW1[k * 256 + n]);
  } else if (o < 360448) {                // nW2T[n][k], n<256,k<256
    int o4 = o - 294912; int n = o4 >> 8, k = o4 & 255;
    wb[O_NW2T + o4] = f2bf(nW2[k * 256 + n]);
  }
}

__global__ void prep_nodes(const float* __restrict__ nodes, u64* __restrict__ nbf) {
  const size_t total = (size_t)BATCH * NN * DN / 4;
  for (size_t i = (size_t)blockIdx.x * 256 + threadIdx.x; i < total;
       i += (size_t)gridDim.x * 256) {
    f32x4 v = ((const f32x4*)nodes)[i];
    nbf[i] = pack4bf(v);
  }
}

__global__ void agg2bf_kernel(const float* __restrict__ agg, u64* __restrict__ aggbf) {
  const size_t total = (size_t)BATCH * NN * DE / 4;
  for (size_t i = (size_t)blockIdx.x * 256 + threadIdx.x; i < total;
       i += (size_t)gridDim.x * 256) {
    f32x4 v = ((const f32x4*)agg)[i];
    aggbf[i] = pack4bf(v);
  }
}

__global__ __launch_bounds__(256) void edge_kernel(
    const float* __restrict__ edges,
    const int* __restrict__ senders, const int* __restrict__ receivers,
    const float* __restrict__ eb1, const float* __restrict__ eb2,
    const u16* __restrict__ eW1T, const u16* __restrict__ eW2T,
    const u16* __restrict__ nodesbf, float* __restrict__ agg,
    float* __restrict__ out_edges) {
  // [128 rows][256 bf16]: rows 0-63 = recv, 64-127 = send.
  // 16B slot s of row r stored at slot (s ^ (r&7))  -> conflict-free col reads.
  // After GEMM1, rows 0-63 (32KB) are reused as hT (u64[4096]).
  __shared__ u16 smem[32768];
  u64* hT = (u64*)smem;

  const int t = threadIdx.x;
  const int lane = t & 63;
  const int wv = t >> 6;        // wave 0..3
  const int lg = lane >> 4;     // lane group 0..3
  const int lr = lane & 15;     // lane row/col 0..15
  const int b = blockIdx.x >> 11;                 // 2048 blocks per batch
  const int e0 = (blockIdx.x << 6) & (NE - 1);    // edge base in batch
  const size_t bNE = (size_t)b * NE;
  const u16* __restrict__ nbf = nodesbf + (size_t)b * NN * DN;

  // ---- stage: gather 64 recv + 64 send rows into LDS (coalesced 512B rows)
  bf16x8 stg[16];
#pragma unroll
  for (int i = 0; i < 16; ++i) {
    int gi = t + 256 * i;                 // 0..4095 over [row 0..127][slot 0..31]
    int row = gi >> 5, slot = gi & 31;
    int idx = (row < 64) ? receivers[bNE + e0 + row]
                         : senders[bNE + e0 + (row - 64)];
    stg[i] = *(const bf16x8*)(nbf + (size_t)idx * DN + slot * 8);
  }
#pragma unroll
  for (int i = 0; i < 16; ++i) {
    int gi = t + 256 * i;
    int row = gi >> 5, slot = gi & 31;
    *(bf16x8*)(smem + row * 256 + ((slot ^ (row & 7)) << 3)) = stg[i];
  }

  int r_ef[4];
#pragma unroll
  for (int ef = 0; ef < 4; ++ef)
    r_ef[ef] = receivers[bNE + e0 + ef * 16 + lr];

  const int nb = wv * 64;  // this wave's hidden-row base

  f32x4 acc1[4][4];
#pragma unroll
  for (int i = 0; i < 4; ++i)
#pragma unroll
    for (int j = 0; j < 4; ++j) acc1[i][j] = (f32x4){0.f, 0.f, 0.f, 0.f};

  __syncthreads();

  // ---- GEMM1: h^T[n][e] over K = 640 (recv | send | edges)
  // kt 0..3 : recv rows from LDS
#pragma unroll 2
  for (int kt = 0; kt < 4; ++kt) {
#pragma unroll
    for (int kf = 0; kf < 2; ++kf) {
      const int k = kt * 64 + kf * 32 + lg * 8;
      const int slot = kt * 8 + kf * 4 + lg;
      bf16x8 xf[4];
#pragma unroll
      for (int nf = 0; nf < 4; ++nf)
        xf[nf] = *(const bf16x8*)(eW1T + (size_t)(nb + nf * 16 + lr) * 640 + k);
      bf16x8 yf[4];
#pragma unroll
      for (int ef = 0; ef < 4; ++ef) {
        int row = ef * 16 + lr;
        yf[ef] = *(const bf16x8*)(smem + row * 256 + ((slot ^ (row & 7)) << 3));
      }
#pragma unroll
      for (int nf = 0; nf < 4; ++nf)
#pragma unroll
        for (int ef = 0; ef < 4; ++ef)
          acc1[nf][ef] = __builtin_amdgcn_mfma_f32_16x16x32_bf16(
              xf[nf], yf[ef], acc1[nf][ef], 0, 0, 0);
    }
  }
  // kt 4..7 : send rows from LDS
#pragma unroll 2
  for (int kt = 4; kt < 8; ++kt) {
#pragma unroll
    for (int kf = 0; kf < 2; ++kf) {
      const int k = kt * 64 + kf * 32 + lg * 8;
      const int slot = (kt - 4) * 8 + kf * 4 + lg;
      bf16x8 xf[4];
#pragma unroll
      for (int nf = 0; nf < 4; ++nf)
        xf[nf] = *(const bf16x8*)(eW1T + (size_t)(nb + nf * 16 + lr) * 640 + k);
      bf16x8 yf[4];
#pragma unroll
      for (int ef = 0; ef < 4; ++ef) {
        int row = ef * 16 + lr;
        yf[ef] = *(const bf16x8*)(smem + (64 + row) * 256 + ((slot ^ (row & 7)) << 3));
      }
#pragma unroll
      for (int nf = 0; nf < 4; ++nf)
#pragma unroll
        for (int ef = 0; ef < 4; ++ef)
          acc1[nf][ef] = __builtin_amdgcn_mfma_f32_16x16x32_bf16(
              xf[nf], yf[ef], acc1[nf][ef], 0, 0, 0);
    }
  }
  // kt 8..9 : edge features direct from global (contiguous rows)
#pragma unroll
  for (int kt = 8; kt < 10; ++kt) {
#pragma unroll
    for (int kf = 0; kf < 2; ++kf) {
      const int k = kt * 64 + kf * 32 + lg * 8;
      bf16x8 xf[4];
#pragma unroll
      for (int nf = 0; nf < 4; ++nf)
        xf[nf] = *(const bf16x8*)(eW1T + (size_t)(nb + nf * 16 + lr) * 640 + k);
      bf16x8 yf[4];
#pragma unroll
      for (int ef = 0; ef < 4; ++ef)
        yf[ef] = load8f_bf(edges + (bNE + e0 + ef * 16 + lr) * DE + (k - 512));
#pragma unroll
      for (int nf = 0; nf < 4; ++nf)
#pragma unroll
        for (int ef = 0; ef < 4; ++ef)
          acc1[nf][ef] = __builtin_amdgcn_mfma_f32_16x16x32_bf16(
              xf[nf], yf[ef], acc1[nf][ef], 0, 0, 0);
    }
  }

  __syncthreads();  // all waves done reading recv region before hT overlay

  // ---- epilogue 1: bias + relu, pack to bf16, write h^T to LDS (over recv)
#pragma unroll
  for (int nf = 0; nf < 4; ++nf) {
    f32x4 bias = *(const f32x4*)(eb1 + nb + nf * 16 + lg * 4);
#pragma unroll
    for (int ef = 0; ef < 4; ++ef) {
      f32x4 v = acc1[nf][ef] + bias;
#pragma unroll
      for (int j = 0; j < 4; ++j) v[j] = v[j] > 0.f ? v[j] : 0.f;
      int e = ef * 16 + lr;
      int s = 16 * wv + nf * 4 + lg;   // slot = n/4
      hT[e * 64 + (s ^ (e & 7))] = pack4bf(v);
    }
  }
  __syncthreads();

  // ---- GEMM2: edges_new^T[o][e] = W2^T . h^T, K = 256
  f32x4 acc2[2][4];
#pragma unroll
  for (int i = 0; i < 2; ++i)
#pragma unroll
    for (int j = 0; j < 4; ++j) acc2[i][j] = (f32x4){0.f, 0.f, 0.f, 0.f};

#pragma unroll 2
  for (int kf = 0; kf < 8; ++kf) {
    bf16x8 x2[2];
#pragma unroll
    for (int of = 0; of < 2; ++of)
      x2[of] = *(const bf16x8*)(eW2T + (size_t)(32 * wv + of * 16 + lr) * 256 + kf * 32 + lg * 8);
    bf16x8 y2[4];
#pragma unroll
    for (int ef = 0; ef < 4; ++ef) {
      int e = ef * 16 + lr;
      int s0 = kf * 8 + lg * 2;
      union { u64 q[2]; bf16x8 v; } uu;
      uu.q[0] = hT[e * 64 + (s0 ^ (e & 7))];
      uu.q[1] = hT[e * 64 + ((s0 + 1) ^ (e & 7))];
      y2[ef] = uu.v;
    }
#pragma unroll
    for (int of = 0; of < 2; ++of)
#pragma unroll
      for (int ef = 0; ef < 4; ++ef)
        acc2[of][ef] = __builtin_amdgcn_mfma_f32_16x16x32_bf16(
            x2[of], y2[ef], acc2[of][ef], 0, 0, 0);
  }

  // ---- epilogue 2: bias, residual edges_out, atomic scatter into agg
#pragma unroll
  for (int of = 0; of < 2; ++of) {
    const int obase = 32 * wv + of * 16 + lg * 4;
    f32x4 b2 = *(const f32x4*)(eb2 + obase);
#pragma unroll
    for (int ef = 0; ef < 4; ++ef) {
      f32x4 en = acc2[of][ef] + b2;  // edges_new
      size_t erow = bNE + e0 + ef * 16 + lr;
      f32x4 eold = *(const f32x4*)(edges + erow * DE + obase);
      *(f32x4*)(out_edges + erow * DE + obase) = eold + en;
      float* ap = agg + ((size_t)b * NN + r_ef[ef]) * DE + obase;
      atomicAdd(ap + 0, en[0]);
      atomicAdd(ap + 1, en[1]);
      atomicAdd(ap + 2, en[2]);
      atomicAdd(ap + 3, en[3]);
    }
  }
}

__global__ __launch_bounds__(256) void node_kernel(
    const float* __restrict__ nodes,
    const float* __restrict__ nb1, const float* __restrict__ nb2,
    const u16* __restrict__ nW1T, const u16* __restrict__ nW2T,
    const u16* __restrict__ nodesbf, const u16* __restrict__ aggbf,
    float* __restrict__ out_nodes) {
  __shared__ u64 hT[4096];

  const int t = threadIdx.x;
  const int lane = t & 63;
  const int wv = t >> 6;
  const int lg = lane >> 4;
  const int lr = lane & 15;
  const int b = blockIdx.x >> 8;                  // 256 blocks per batch
  const int m0 = (blockIdx.x << 6) & (NN - 1);

  const u16* __restrict__ nbf = nodesbf + (size_t)b * NN * DN;
  const u16* __restrict__ abf = aggbf + (size_t)b * NN * DE;
  const int nb = wv * 64;

  f32x4 acc1[4][4];
#pragma unroll
  for (int i = 0; i < 4; ++i)
#pragma unroll
    for (int j = 0; j < 4; ++j) acc1[i][j] = (f32x4){0.f, 0.f, 0.f, 0.f};

  // ---- GEMM1: h2^T over K = 384 (agg 0..127 | nodes 128..383)
#pragma unroll 2
  for (int kt = 0; kt < 6; ++kt) {
#pragma unroll
    for (int kf = 0; kf < 2; ++kf) {
      const int k = kt * 64 + kf * 32 + lg * 8;
      bf16x8 xf[4];
#pragma unroll
      for (int nf = 0; nf < 4; ++nf)
        xf[nf] = *(const bf16x8*)(nW1T + (size_t)(nb + nf * 16 + lr) * 384 + k);
      bf16x8 yf[4];
      if (kt < 2) {
#pragma unroll
        for (int ef = 0; ef < 4; ++ef)
          yf[ef] = *(const bf16x8*)(abf + (size_t)(m0 + ef * 16 + lr) * DE + k);
      } else {
#pragma unroll
        for (int ef = 0; ef < 4; ++ef)
          yf[ef] = *(const bf16x8*)(nbf + (size_t)(m0 + ef * 16 + lr) * DN + (k - 128));
      }
#pragma unroll
      for (int nf = 0; nf < 4; ++nf)
#pragma unroll
        for (int ef = 0; ef < 4; ++ef)
          acc1[nf][ef] = __builtin_amdgcn_mfma_f32_16x16x32_bf16(
              xf[nf], yf[ef], acc1[nf][ef], 0, 0, 0);
    }
  }

  // ---- epilogue 1
#pragma unroll
  for (int nf = 0; nf < 4; ++nf) {
    f32x4 bias = *(const f32x4*)(nb1 + nb + nf * 16 + lg * 4);
#pragma unroll
    for (int ef = 0; ef < 4; ++ef) {
      f32x4 v = acc1[nf][ef] + bias;
#pragma unroll
      for (int j = 0; j < 4; ++j) v[j] = v[j] > 0.f ? v[j] : 0.f;
      int e = ef * 16 + lr;
      int s = 16 * wv + nf * 4 + lg;
      hT[e * 64 + (s ^ (e & 7))] = pack4bf(v);
    }
  }
  __syncthreads();

  // ---- GEMM2: nodes_new^T[o][m], K = 256
  f32x4 acc2[4][4];
#pragma unroll
  for (int i = 0; i < 4; ++i)
#pragma unroll
    for (int j = 0; j < 4; ++j) acc2[i][j] = (f32x4){0.f, 0.f, 0.f, 0.f};

#pragma unroll 2
  for (int kf = 0; kf < 8; ++kf) {
    bf16x8 x2[4];
#pragma unroll
    for (int of = 0; of < 4; ++of)
      x2[of] = *(const bf16x8*)(nW2T + (size_t)(64 * wv + of * 16 + lr) * 256 + kf * 32 + lg * 8);
    bf16x8 y2[4];
#pragma unroll
    for (int ef = 0; ef < 4; ++ef) {
      int e = ef * 16 + lr;
      int s0 = kf * 8 + lg * 2;
      union { u64 q[2]; bf16x8 v; } uu;
      uu.q[0] = hT[e * 64 + (s0 ^ (e & 7))];
      uu.q[1] = hT[e * 64 + ((s0 + 1) ^ (e & 7))];
      y2[ef] = uu.v;
    }
#pragma unroll
    for (int of = 0; of < 4; ++of)
#pragma unroll
      for (int ef = 0; ef < 4; ++ef)
        acc2[of][ef] = __builtin_amdgcn_mfma_f32_16x16x32_bf16(
            x2[of], y2[ef], acc2[of][ef], 0, 0, 0);
  }

  // ---- epilogue 2: bias + residual
#pragma unroll
  for (int of = 0; of < 4; ++of) {
    const int obase = 64 * wv + of * 16 + lg * 4;
    f32x4 b2 = *(const f32x4*)(nb2 + obase);
#pragma unroll
    for (int ef = 0; ef < 4; ++ef) {
      f32x4 nn = acc2[of][ef] + b2;
      size_t mrow = (size_t)b * NN + m0 + ef * 16 + lr;
      f32x4 nold = *(const f32x4*)(nodes + mrow * DN + obase);
      *(f32x4*)(out_nodes + mrow * DN + obase) = nold + nn;
    }
  }
}

extern "C" void kernel_launch(void* const* d_in, const int* in_sizes, int n_in,
                              void* d_out, int out_size, void* d_ws, size_t ws_size,
                              hipStream_t stream) {
  const float* nodes = (const float*)d_in[0];
  const float* edges = (const float*)d_in[1];
  const int* senders = (const int*)d_in[2];
  const int* receivers = (const int*)d_in[3];
  const float* eW1 = (const float*)d_in[4];
  const float* eb1 = (const float*)d_in[5];
  const float* eW2 = (const float*)d_in[6];
  const float* eb2 = (const float*)d_in[7];
  const float* nW1 = (const float*)d_in[8];
  const float* nb1 = (const float*)d_in[9];
  const float* nW2 = (const float*)d_in[10];
  const float* nb2 = (const float*)d_in[11];

  char* ws = (char*)d_ws;
  u16* wb = (u16*)(ws + WS_EW1T);
  u16* nodesbf = (u16*)(ws + WS_NODESBF);
  float* agg = (float*)(ws + WS_AGG);
  u16* aggbf = (u16*)(ws + WS_AGGBF);
  float* out = (float*)d_out;

  hipMemsetAsync(agg, 0, (size_t)BATCH * NN * DE * sizeof(float), stream);
  prep_weights<<<1408, 256, 0, stream>>>(eW1, eW2, nW1, nW2, wb);
  prep_nodes<<<2048, 256, 0, stream>>>(nodes, (u64*)nodesbf);
  edge_kernel<<<4096, 256, 0, stream>>>(edges, senders, receivers, eb1, eb2,
                                        wb + O_EW1T, wb + O_EW2T, nodesbf, agg,
                                        out + (size_t)BATCH * NN * DN);
  agg2bf_kernel<<<1024, 256, 0, stream>>>(agg, (u64*)aggbf);
  node_kernel<<<512, 256, 0, stream>>>(nodes, nb1, nb2, wb + O_NW1T, wb + O_NW2T,
                                       nodesbf, aggbf, out);
  (void)in_sizes; (void)n_in; (void)out_size; (void)ws_size;
}

// Round 4
// 816.415 us; speedup vs baseline: 1.1482x; 1.0690x over previous
//
#include <hip/hip_runtime.h>
#include <hip/hip_bf16.h>

// InteractionNetworkLayer on MI355X — round 3 (resubmit; prior bench hit
// GPUAcquisitionTimeout): algebraic hoist of the gather-GEMM.
//
// Key identity: edge MLP input is [nodes[r] | nodes[s] | edges], so
//   h = relu(P[r] + Q[s] + edges*W1c + b1),  P = nodes*W1a, Q = nodes*W1b
// P,Q are per-NODE (16K rows) instead of per-EDGE (131K rows): edge-path
// FLOPs drop 103 -> ~50 GFLOP, and the fused edge kernel only runs
// K=128 (R-GEMM) + K=256 (GEMM2) with 128KB of L2-hot weights.
// LDS 48KB -> 3 blocks/CU; node kernel re-tiled to 32 rows -> 4 blocks/CU.

typedef __attribute__((ext_vector_type(8))) short bf16x8;
typedef __attribute__((ext_vector_type(4))) float f32x4;
typedef unsigned long long u64;
typedef unsigned short u16;
typedef unsigned int u32;

#define BATCH 2
#define NN 16384
#define NE 131072
#define DN 256
#define DE 128

// u16-unit offsets inside the weight block
#define O_EW1A 0        // [256h][256k]   recv block of eW1
#define O_EW1B 65536    // [256h][256k]   send block
#define O_EW1C 131072   // [256h][128k]   edge-feat block
#define O_EW2T 163840   // [128o][256k]
#define O_NW1T 196608   // [256h][384k]
#define O_NW2T 294912   // [256o][256k]
#define W_TOTAL 360448

// ws byte offsets
#define WS_WB      0u
#define WS_NODESBF 720896u    // 2*16384*256 bf16 = 16777216 B
#define WS_AGG     17498112u  // 2*16384*128 f32  = 16777216 B
#define WS_AGGBF   34275328u  // 2*16384*128 bf16 =  8388608 B
#define WS_PBUF    42663936u  // 2*16384*256 bf16 = 16777216 B
#define WS_QBUF    59441152u  // 2*16384*256 bf16 = 16777216 B
// end: 76218368 B

__device__ inline u16 f2bf(float f) {
  u32 u = __builtin_bit_cast(u32, f);
  u32 r = u + 0x7FFFu + ((u >> 16) & 1u);
  return (u16)(r >> 16);
}

__device__ inline float bf2f(u16 h) {
  u32 u = ((u32)h) << 16;
  return __builtin_bit_cast(float, u);
}

__device__ inline u64 pack4bf(f32x4 v) {
  return (u64)f2bf(v[0]) | ((u64)f2bf(v[1]) << 16) |
         ((u64)f2bf(v[2]) << 32) | ((u64)f2bf(v[3]) << 48);
}

__device__ inline bf16x8 load8f_bf(const float* __restrict__ p) {
  f32x4 a = *(const f32x4*)p;
  f32x4 c = *(const f32x4*)(p + 4);
  bf16x8 r;
  r[0] = (short)f2bf(a[0]); r[1] = (short)f2bf(a[1]);
  r[2] = (short)f2bf(a[2]); r[3] = (short)f2bf(a[3]);
  r[4] = (short)f2bf(c[0]); r[5] = (short)f2bf(c[1]);
  r[6] = (short)f2bf(c[2]); r[7] = (short)f2bf(c[3]);
  return r;
}

__global__ void prep_weights(const float* __restrict__ eW1, const float* __restrict__ eW2,
                             const float* __restrict__ nW1, const float* __restrict__ nW2,
                             u16* __restrict__ wb) {
  int o = blockIdx.x * 256 + threadIdx.x;
  if (o < 65536) {                        // eW1aT[h][k], k<256 (recv rows of eW1)
    int h = o >> 8, k = o & 255;
    wb[O_EW1A + o] = f2bf(eW1[k * 256 + h]);
  } else if (o < 131072) {                // eW1bT[h][k], rows 256..511
    int o2 = o - 65536; int h = o2 >> 8, k = o2 & 255;
    wb[O_EW1B + o2] = f2bf(eW1[(256 + k) * 256 + h]);
  } else if (o < 163840) {                // eW1cT[h][k], k<128, rows 512..639
    int o3 = o - 131072; int h = o3 >> 7, k = o3 & 127;
    wb[O_EW1C + o3] = f2bf(eW1[(512 + k) * 256 + h]);
  } else if (o < 196608) {                // eW2T[o][k], o<128,k<256
    int o4 = o - 163840; int n = o4 >> 8, k = o4 & 255;
    wb[O_EW2T + o4] = f2bf(eW2[k * 128 + n]);
  } else if (o < 294912) {                // nW1T[h][k], h<256,k<384
    int o5 = o - 196608; int n = o5 / 384, k = o5 % 384;
    wb[O_NW1T + o5] = f2bf(nW1[k * 256 + n]);
  } else if (o < 360448) {                // nW2T[o][k], o<256,k<256
    int o6 = o - 294912; int n = o6 >> 8, k = o6 & 255;
    wb[O_NW2T + o6] = f2bf(nW2[k * 256 + n]);
  }
}

__global__ void prep_nodes(const float* __restrict__ nodes, u64* __restrict__ nbf) {
  const size_t total = (size_t)BATCH * NN * DN / 4;
  for (size_t i = (size_t)blockIdx.x * 256 + threadIdx.x; i < total;
       i += (size_t)gridDim.x * 256) {
    f32x4 v = ((const f32x4*)nodes)[i];
    nbf[i] = pack4bf(v);
  }
}

__global__ void agg2bf_kernel(const float* __restrict__ agg, u64* __restrict__ aggbf) {
  const size_t total = (size_t)BATCH * NN * DE / 4;
  for (size_t i = (size_t)blockIdx.x * 256 + threadIdx.x; i < total;
       i += (size_t)gridDim.x * 256) {
    f32x4 v = ((const f32x4*)agg)[i];
    aggbf[i] = pack4bf(v);
  }
}

// P = nodes*W1a, Q = nodes*W1b  (dense per-node GEMMs, bf16 out, row-major [node][h])
__global__ __launch_bounds__(256) void pq_kernel(
    const u16* __restrict__ nodesbf, const u16* __restrict__ wb,
    u16* __restrict__ pbuf, u16* __restrict__ qbuf) {
  const int t = threadIdx.x;
  const int lane = t & 63, wv = t >> 6, lg = lane >> 4, lr = lane & 15;
  const int sel = blockIdx.x >> 9;
  const int bb = blockIdx.x & 511;
  const int b = bb >> 8;
  const int m0 = (bb & 255) << 6;
  const u16* __restrict__ W = wb + (sel ? O_EW1B : O_EW1A);
  u16* __restrict__ outb = (sel ? qbuf : pbuf) + (size_t)b * NN * DN;
  const u16* __restrict__ nbf = nodesbf + (size_t)b * NN * DN;
  const int nb = wv * 64;

  f32x4 acc[4][4];
#pragma unroll
  for (int i = 0; i < 4; ++i)
#pragma unroll
    for (int j = 0; j < 4; ++j) acc[i][j] = (f32x4){0.f, 0.f, 0.f, 0.f};

#pragma unroll 2
  for (int kt = 0; kt < 8; ++kt) {
    const int k = kt * 32 + lg * 8;
    bf16x8 xf[4];
#pragma unroll
    for (int nf = 0; nf < 4; ++nf)
      xf[nf] = *(const bf16x8*)(W + (size_t)(nb + nf * 16 + lr) * 256 + k);
    bf16x8 yf[4];
#pragma unroll
    for (int ef = 0; ef < 4; ++ef)
      yf[ef] = *(const bf16x8*)(nbf + (size_t)(m0 + ef * 16 + lr) * 256 + k);
#pragma unroll
    for (int nf = 0; nf < 4; ++nf)
#pragma unroll
      for (int ef = 0; ef < 4; ++ef)
        acc[nf][ef] = __builtin_amdgcn_mfma_f32_16x16x32_bf16(
            xf[nf], yf[ef], acc[nf][ef], 0, 0, 0);
  }

#pragma unroll
  for (int nf = 0; nf < 4; ++nf)
#pragma unroll
    for (int ef = 0; ef < 4; ++ef) {
      int row = m0 + ef * 16 + lr;
      *(u64*)(outb + (size_t)row * 256 + nb + nf * 16 + lg * 4) = pack4bf(acc[nf][ef]);
    }
}

__global__ __launch_bounds__(256) void edge_kernel(
    const float* __restrict__ edges,
    const int* __restrict__ senders, const int* __restrict__ receivers,
    const float* __restrict__ eb1, const float* __restrict__ eb2,
    const u16* __restrict__ eW1cT, const u16* __restrict__ eW2T,
    const u16* __restrict__ pbuf, const u16* __restrict__ qbuf,
    float* __restrict__ agg, float* __restrict__ out_edges) {
  // S: [64 e][256 h] bf16 (32KB, 16B-slot XOR swizzle) = P[r]+Q[s]
  // E: [64 e][128 k] bf16 (16KB, 16B-slot XOR swizzle) = edge feats
  // hT overlays S after epilogue-1 (per-wave byte-stripes are disjoint:
  // wave wv reads S bytes [128wv,128wv+128) of each row, then writes hT
  // into exactly that stripe; within-wave all S reads precede hT writes).
  __shared__ __align__(16) u16 smem[24576];
  u16* S = smem;
  u16* E = smem + 16384;
  u64* hT = (u64*)smem;

  const int t = threadIdx.x;
  const int lane = t & 63, wv = t >> 6, lg = lane >> 4, lr = lane & 15;
  const int b = blockIdx.x >> 11;
  const int e0 = (blockIdx.x << 6) & (NE - 1);
  const size_t bNE = (size_t)b * NE;
  const u16* __restrict__ Pb = pbuf + (size_t)b * NN * DN;
  const u16* __restrict__ Qb = qbuf + (size_t)b * NN * DN;

  int r_ef[4];
#pragma unroll
  for (int ef = 0; ef < 4; ++ef)
    r_ef[ef] = receivers[bNE + e0 + ef * 16 + lr];

  // ---- stage S = P[recv] + Q[send]  (coalesced per row: 2 rows per wave-instr)
#pragma unroll
  for (int i = 0; i < 8; ++i) {
    int gi = t + 256 * i;              // [row 0..63][slot 0..31]
    int row = gi >> 5, slot = gi & 31;
    int ri = receivers[bNE + e0 + row];
    int si = senders[bNE + e0 + row];
    bf16x8 pv = *(const bf16x8*)(Pb + (size_t)ri * 256 + slot * 8);
    bf16x8 qv = *(const bf16x8*)(Qb + (size_t)si * 256 + slot * 8);
    bf16x8 sv;
#pragma unroll
    for (int j = 0; j < 8; ++j)
      sv[j] = (short)f2bf(bf2f((u16)pv[j]) + bf2f((u16)qv[j]));
    *(bf16x8*)(S + row * 256 + ((slot ^ (row & 7)) << 3)) = sv;
  }

  // ---- stage E = bf16(edges tile)
#pragma unroll
  for (int i = 0; i < 4; ++i) {
    int gi = t + 256 * i;              // [row 0..63][slot 0..15]
    int row = gi >> 4, slot = gi & 15;
    *(bf16x8*)(E + row * 128 + ((slot ^ (row & 7)) << 3)) =
        load8f_bf(edges + (bNE + e0 + row) * DE + slot * 8);
  }
  __syncthreads();

  const int nb = wv * 64;
  f32x4 acc1[4][4];
#pragma unroll
  for (int i = 0; i < 4; ++i)
#pragma unroll
    for (int j = 0; j < 4; ++j) acc1[i][j] = (f32x4){0.f, 0.f, 0.f, 0.f};

  // ---- R-GEMM: acc1 = W1c^T . E^T   (K = 128, weights 64KB L2-hot)
#pragma unroll
  for (int kt = 0; kt < 4; ++kt) {
    const int k = kt * 32 + lg * 8;
    const int slot = kt * 4 + lg;
    bf16x8 xf[4];
#pragma unroll
    for (int nf = 0; nf < 4; ++nf)
      xf[nf] = *(const bf16x8*)(eW1cT + (size_t)(nb + nf * 16 + lr) * 128 + k);
    bf16x8 yf[4];
#pragma unroll
    for (int ef = 0; ef < 4; ++ef) {
      int row = ef * 16 + lr;
      yf[ef] = *(const bf16x8*)(E + row * 128 + ((slot ^ (row & 7)) << 3));
    }
#pragma unroll
    for (int nf = 0; nf < 4; ++nf)
#pragma unroll
      for (int ef = 0; ef < 4; ++ef)
        acc1[nf][ef] = __builtin_amdgcn_mfma_f32_16x16x32_bf16(
            xf[nf], yf[ef], acc1[nf][ef], 0, 0, 0);
  }

  // ---- epilogue 1: h = relu(acc1 + S + b1) -> hT (read ALL S frags first,
  //      then write hT — in-place overlay safety within the wave)
  u64 sv64[4][4];
#pragma unroll
  for (int nf = 0; nf < 4; ++nf)
#pragma unroll
    for (int ef = 0; ef < 4; ++ef) {
      int row = ef * 16 + lr;
      int s16 = 8 * wv + nf * 2 + (lg >> 1);
      sv64[nf][ef] = *(const u64*)(S + row * 256 + ((s16 ^ (row & 7)) << 3) + ((lg & 1) << 2));
    }
#pragma unroll
  for (int nf = 0; nf < 4; ++nf) {
    f32x4 bias = *(const f32x4*)(eb1 + nb + nf * 16 + lg * 4);
#pragma unroll
    for (int ef = 0; ef < 4; ++ef) {
      u64 q = sv64[nf][ef];
      f32x4 v;
#pragma unroll
      for (int j = 0; j < 4; ++j) {
        float sj = bf2f((u16)(q >> (16 * j)));
        float x = acc1[nf][ef][j] + sj + bias[j];
        v[j] = x > 0.f ? x : 0.f;
      }
      int e = ef * 16 + lr;
      int s = 16 * wv + nf * 4 + lg;
      hT[e * 64 + (s ^ (e & 7))] = pack4bf(v);
    }
  }
  __syncthreads();

  // ---- GEMM2: edges_new^T = W2^T . h^T, K = 256 (weights 64KB L2-hot)
  f32x4 acc2[2][4];
#pragma unroll
  for (int i = 0; i < 2; ++i)
#pragma unroll
    for (int j = 0; j < 4; ++j) acc2[i][j] = (f32x4){0.f, 0.f, 0.f, 0.f};

#pragma unroll 2
  for (int kf = 0; kf < 8; ++kf) {
    bf16x8 x2[2];
#pragma unroll
    for (int of = 0; of < 2; ++of)
      x2[of] = *(const bf16x8*)(eW2T + (size_t)(32 * wv + of * 16 + lr) * 256 + kf * 32 + lg * 8);
    bf16x8 y2[4];
#pragma unroll
    for (int ef = 0; ef < 4; ++ef) {
      int e = ef * 16 + lr;
      int s0 = kf * 8 + lg * 2;
      union { u64 q[2]; bf16x8 v; } uu;
      uu.q[0] = hT[e * 64 + (s0 ^ (e & 7))];
      uu.q[1] = hT[e * 64 + ((s0 + 1) ^ (e & 7))];
      y2[ef] = uu.v;
    }
#pragma unroll
    for (int of = 0; of < 2; ++of)
#pragma unroll
      for (int ef = 0; ef < 4; ++ef)
        acc2[of][ef] = __builtin_amdgcn_mfma_f32_16x16x32_bf16(
            x2[of], y2[ef], acc2[of][ef], 0, 0, 0);
  }

  // ---- epilogue 2: residual edges_out + atomic scatter into agg
#pragma unroll
  for (int of = 0; of < 2; ++of) {
    const int obase = 32 * wv + of * 16 + lg * 4;
    f32x4 b2 = *(const f32x4*)(eb2 + obase);
#pragma unroll
    for (int ef = 0; ef < 4; ++ef) {
      f32x4 en = acc2[of][ef] + b2;
      size_t erow = bNE + e0 + ef * 16 + lr;
      f32x4 eold = *(const f32x4*)(edges + erow * DE + obase);
      *(f32x4*)(out_edges + erow * DE + obase) = eold + en;
      float* ap = agg + ((size_t)b * NN + r_ef[ef]) * DE + obase;
      atomicAdd(ap + 0, en[0]);
      atomicAdd(ap + 1, en[1]);
      atomicAdd(ap + 2, en[2]);
      atomicAdd(ap + 3, en[3]);
    }
  }
}

// node MLP: 32-row tiles, 1024 blocks -> 4 blocks/CU for latency hiding
__global__ __launch_bounds__(256) void node_kernel(
    const float* __restrict__ nodes,
    const float* __restrict__ nb1v, const float* __restrict__ nb2v,
    const u16* __restrict__ nW1T, const u16* __restrict__ nW2T,
    const u16* __restrict__ nodesbf, const u16* __restrict__ aggbf,
    float* __restrict__ out_nodes) {
  __shared__ __align__(16) u64 hT[2048];  // [32 m][64 slots]

  const int t = threadIdx.x;
  const int lane = t & 63, wv = t >> 6, lg = lane >> 4, lr = lane & 15;
  const int b = blockIdx.x >> 9;
  const int m0 = (blockIdx.x & 511) << 5;

  const u16* __restrict__ nbf = nodesbf + (size_t)b * NN * DN;
  const u16* __restrict__ abf = aggbf + (size_t)b * NN * DE;
  const int nb = wv * 64;

  f32x4 acc1[4][2];
#pragma unroll
  for (int i = 0; i < 4; ++i)
#pragma unroll
    for (int j = 0; j < 2; ++j) acc1[i][j] = (f32x4){0.f, 0.f, 0.f, 0.f};

  // ---- GEMM1: K = 384 (agg 0..127 | nodes 128..383)
#pragma unroll 2
  for (int kt = 0; kt < 12; ++kt) {
    const int k = kt * 32 + lg * 8;
    bf16x8 xf[4];
#pragma unroll
    for (int nf = 0; nf < 4; ++nf)
      xf[nf] = *(const bf16x8*)(nW1T + (size_t)(nb + nf * 16 + lr) * 384 + k);
    bf16x8 yf[2];
    if (kt < 4) {
#pragma unroll
      for (int ef = 0; ef < 2; ++ef)
        yf[ef] = *(const bf16x8*)(abf + (size_t)(m0 + ef * 16 + lr) * DE + k);
    } else {
#pragma unroll
      for (int ef = 0; ef < 2; ++ef)
        yf[ef] = *(const bf16x8*)(nbf + (size_t)(m0 + ef * 16 + lr) * DN + (k - 128));
    }
#pragma unroll
    for (int nf = 0; nf < 4; ++nf)
#pragma unroll
      for (int ef = 0; ef < 2; ++ef)
        acc1[nf][ef] = __builtin_amdgcn_mfma_f32_16x16x32_bf16(
            xf[nf], yf[ef], acc1[nf][ef], 0, 0, 0);
  }

  // ---- epilogue 1
#pragma unroll
  for (int nf = 0; nf < 4; ++nf) {
    f32x4 bias = *(const f32x4*)(nb1v + nb + nf * 16 + lg * 4);
#pragma unroll
    for (int ef = 0; ef < 2; ++ef) {
      f32x4 v = acc1[nf][ef] + bias;
#pragma unroll
      for (int j = 0; j < 4; ++j) v[j] = v[j] > 0.f ? v[j] : 0.f;
      int e = ef * 16 + lr;
      int s = 16 * wv + nf * 4 + lg;
      hT[e * 64 + (s ^ (e & 7))] = pack4bf(v);
    }
  }
  __syncthreads();

  // ---- GEMM2: K = 256
  f32x4 acc2[4][2];
#pragma unroll
  for (int i = 0; i < 4; ++i)
#pragma unroll
    for (int j = 0; j < 2; ++j) acc2[i][j] = (f32x4){0.f, 0.f, 0.f, 0.f};

#pragma unroll 2
  for (int kf = 0; kf < 8; ++kf) {
    bf16x8 x2[4];
#pragma unroll
    for (int of = 0; of < 4; ++of)
      x2[of] = *(const bf16x8*)(nW2T + (size_t)(64 * wv + of * 16 + lr) * 256 + kf * 32 + lg * 8);
    bf16x8 y2[2];
#pragma unroll
    for (int ef = 0; ef < 2; ++ef) {
      int e = ef * 16 + lr;
      int s0 = kf * 8 + lg * 2;
      union { u64 q[2]; bf16x8 v; } uu;
      uu.q[0] = hT[e * 64 + (s0 ^ (e & 7))];
      uu.q[1] = hT[e * 64 + ((s0 + 1) ^ (e & 7))];
      y2[ef] = uu.v;
    }
#pragma unroll
    for (int of = 0; of < 4; ++of)
#pragma unroll
      for (int ef = 0; ef < 2; ++ef)
        acc2[of][ef] = __builtin_amdgcn_mfma_f32_16x16x32_bf16(
            x2[of], y2[ef], acc2[of][ef], 0, 0, 0);
  }

  // ---- epilogue 2: bias + residual
#pragma unroll
  for (int of = 0; of < 4; ++of) {
    const int obase = 64 * wv + of * 16 + lg * 4;
    f32x4 b2 = *(const f32x4*)(nb2v + obase);
#pragma unroll
    for (int ef = 0; ef < 2; ++ef) {
      f32x4 nn = acc2[of][ef] + b2;
      size_t mrow = (size_t)b * NN + m0 + ef * 16 + lr;
      f32x4 nold = *(const f32x4*)(nodes + mrow * DN + obase);
      *(f32x4*)(out_nodes + mrow * DN + obase) = nold + nn;
    }
  }
}

extern "C" void kernel_launch(void* const* d_in, const int* in_sizes, int n_in,
                              void* d_out, int out_size, void* d_ws, size_t ws_size,
                              hipStream_t stream) {
  const float* nodes = (const float*)d_in[0];
  const float* edges = (const float*)d_in[1];
  const int* senders = (const int*)d_in[2];
  const int* receivers = (const int*)d_in[3];
  const float* eW1 = (const float*)d_in[4];
  const float* eb1 = (const float*)d_in[5];
  const float* eW2 = (const float*)d_in[6];
  const float* eb2 = (const float*)d_in[7];
  const float* nW1 = (const float*)d_in[8];
  const float* nb1 = (const float*)d_in[9];
  const float* nW2 = (const float*)d_in[10];
  const float* nb2 = (const float*)d_in[11];

  char* ws = (char*)d_ws;
  u16* wb = (u16*)(ws + WS_WB);
  u16* nodesbf = (u16*)(ws + WS_NODESBF);
  float* agg = (float*)(ws + WS_AGG);
  u16* aggbf = (u16*)(ws + WS_AGGBF);
  u16* pbuf = (u16*)(ws + WS_PBUF);
  u16* qbuf = (u16*)(ws + WS_QBUF);
  float* out = (float*)d_out;

  hipMemsetAsync(agg, 0, (size_t)BATCH * NN * DE * sizeof(float), stream);
  prep_weights<<<1408, 256, 0, stream>>>(eW1, eW2, nW1, nW2, wb);
  prep_nodes<<<2048, 256, 0, stream>>>(nodes, (u64*)nodesbf);
  pq_kernel<<<1024, 256, 0, stream>>>(nodesbf, wb, pbuf, qbuf);
  edge_kernel<<<4096, 256, 0, stream>>>(edges, senders, receivers, eb1, eb2,
                                        wb + O_EW1C, wb + O_EW2T, pbuf, qbuf,
                                        agg, out + (size_t)BATCH * NN * DN);
  agg2bf_kernel<<<1024, 256, 0, stream>>>(agg, (u64*)aggbf);
  node_kernel<<<1024, 256, 0, stream>>>(nodes, nb1, nb2, wb + O_NW1T, wb + O_NW2T,
                                        nodesbf, aggbf, out);
  (void)in_sizes; (void)n_in; (void)out_size; (void)ws_size;
}

// Round 5
// 583.380 us; speedup vs baseline: 1.6068x; 1.3995x over previous
//
#include <hip/hip_runtime.h>
#include <hip/hip_bf16.h>

// InteractionNetworkLayer on MI355X — round 5: CSR gather replaces atomic scatter.
//
// Round-4 diagnosis: edge_kernel WRITE_SIZE 703MB vs 134MB streaming ideal —
// the 33.5M scattered 4B atomicAdds dominate (fabric RMW + serialization).
// Fix: no atomics. Build CSR (hist -> scan -> fill) over receivers, then
// gather_kernel sums edges_new per node (en = edges_out - edges, exact in f32)
// into bf16 agg. CSR arrays live in the dead f32-agg ws slot (no ws growth).
//
// Pipeline: prep_weights | prep_nodes | pq | hist | scan | fill
//           | edge (no atomics) | gather | node

typedef __attribute__((ext_vector_type(8))) short bf16x8;
typedef __attribute__((ext_vector_type(4))) float f32x4;
typedef __attribute__((ext_vector_type(2))) float f32x2;
typedef unsigned long long u64;
typedef unsigned short u16;
typedef unsigned int u32;

#define BATCH 2
#define NN 16384
#define NE 131072
#define DN 256
#define DE 128

// u16-unit offsets inside the weight block
#define O_EW1A 0        // [256h][256k]   recv block of eW1
#define O_EW1B 65536    // [256h][256k]   send block
#define O_EW1C 131072   // [256h][128k]   edge-feat block
#define O_EW2T 163840   // [128o][256k]
#define O_NW1T 196608   // [256h][384k]
#define O_NW2T 294912   // [256o][256k]

// ws byte offsets
#define WS_WB      0u
#define WS_NODESBF 720896u    // 2*16384*256 bf16 = 16777216 B
#define WS_CNT     17498112u  // 32768 u32 (reuses dead f32-agg slot)
#define WS_OFF     17629184u  // 32768 u32
#define WS_CUR     17760256u  // 32768 u32
#define WS_EIDX    17891328u  // 262144 u32 = 1MB
#define WS_AGGBF   34275328u  // 2*16384*128 bf16 = 8388608 B
#define WS_PBUF    42663936u  // 2*16384*256 bf16 = 16777216 B
#define WS_QBUF    59441152u  // 2*16384*256 bf16 = 16777216 B
// end: 76218368 B

__device__ inline u16 f2bf(float f) {
  u32 u = __builtin_bit_cast(u32, f);
  u32 r = u + 0x7FFFu + ((u >> 16) & 1u);
  return (u16)(r >> 16);
}

__device__ inline float bf2f(u16 h) {
  u32 u = ((u32)h) << 16;
  return __builtin_bit_cast(float, u);
}

__device__ inline u64 pack4bf(f32x4 v) {
  return (u64)f2bf(v[0]) | ((u64)f2bf(v[1]) << 16) |
         ((u64)f2bf(v[2]) << 32) | ((u64)f2bf(v[3]) << 48);
}

__device__ inline bf16x8 load8f_bf(const float* __restrict__ p) {
  f32x4 a = *(const f32x4*)p;
  f32x4 c = *(const f32x4*)(p + 4);
  bf16x8 r;
  r[0] = (short)f2bf(a[0]); r[1] = (short)f2bf(a[1]);
  r[2] = (short)f2bf(a[2]); r[3] = (short)f2bf(a[3]);
  r[4] = (short)f2bf(c[0]); r[5] = (short)f2bf(c[1]);
  r[6] = (short)f2bf(c[2]); r[7] = (short)f2bf(c[3]);
  return r;
}

__global__ void prep_weights(const float* __restrict__ eW1, const float* __restrict__ eW2,
                             const float* __restrict__ nW1, const float* __restrict__ nW2,
                             u16* __restrict__ wb) {
  int o = blockIdx.x * 256 + threadIdx.x;
  if (o < 65536) {                        // eW1aT[h][k], k<256 (recv rows of eW1)
    int h = o >> 8, k = o & 255;
    wb[O_EW1A + o] = f2bf(eW1[k * 256 + h]);
  } else if (o < 131072) {                // eW1bT[h][k], rows 256..511
    int o2 = o - 65536; int h = o2 >> 8, k = o2 & 255;
    wb[O_EW1B + o2] = f2bf(eW1[(256 + k) * 256 + h]);
  } else if (o < 163840) {                // eW1cT[h][k], k<128, rows 512..639
    int o3 = o - 131072; int h = o3 >> 7, k = o3 & 127;
    wb[O_EW1C + o3] = f2bf(eW1[(512 + k) * 256 + h]);
  } else if (o < 196608) {                // eW2T[o][k], o<128,k<256
    int o4 = o - 163840; int n = o4 >> 8, k = o4 & 255;
    wb[O_EW2T + o4] = f2bf(eW2[k * 128 + n]);
  } else if (o < 294912) {                // nW1T[h][k], h<256,k<384
    int o5 = o - 196608; int n = o5 / 384, k = o5 % 384;
    wb[O_NW1T + o5] = f2bf(nW1[k * 256 + n]);
  } else if (o < 360448) {                // nW2T[o][k], o<256,k<256
    int o6 = o - 294912; int n = o6 >> 8, k = o6 & 255;
    wb[O_NW2T + o6] = f2bf(nW2[k * 256 + n]);
  }
}

__global__ void prep_nodes(const float* __restrict__ nodes, u64* __restrict__ nbf) {
  const size_t total = (size_t)BATCH * NN * DN / 4;
  for (size_t i = (size_t)blockIdx.x * 256 + threadIdx.x; i < total;
       i += (size_t)gridDim.x * 256) {
    f32x4 v = ((const f32x4*)nodes)[i];
    nbf[i] = pack4bf(v);
  }
}

// ---- CSR build ----
__global__ void hist_kernel(const int* __restrict__ receivers, u32* __restrict__ cnt) {
  int i = blockIdx.x * 256 + threadIdx.x;      // 0..262143, exact grid
  int b = i >> 17, e = i & (NE - 1);
  int r = receivers[(size_t)b * NE + e];
  atomicAdd(&cnt[b * NN + r], 1u);
}

__global__ __launch_bounds__(1024) void scan_kernel(const u32* __restrict__ cnt,
                                                    u32* __restrict__ off) {
  __shared__ u32 part[1024];
  const int t = threadIdx.x;
  u32 loc[32];
  u32 s = 0;
#pragma unroll
  for (int j = 0; j < 32; ++j) { loc[j] = s; s += cnt[t * 32 + j]; }
  part[t] = s;
  __syncthreads();
  // Hillis-Steele inclusive scan over 1024 partials
  for (int d = 1; d < 1024; d <<= 1) {
    u32 v = (t >= d) ? part[t - d] : 0u;
    __syncthreads();
    part[t] += v;
    __syncthreads();
  }
  u32 base = (t == 0) ? 0u : part[t - 1];
#pragma unroll
  for (int j = 0; j < 32; ++j) off[t * 32 + j] = base + loc[j];
}

__global__ void fill_kernel(const int* __restrict__ receivers,
                            const u32* __restrict__ off, u32* __restrict__ cur,
                            u32* __restrict__ eidx) {
  int i = blockIdx.x * 256 + threadIdx.x;
  int b = i >> 17, e = i & (NE - 1);
  int r = receivers[(size_t)b * NE + e];
  u32 p = atomicAdd(&cur[b * NN + r], 1u);
  eidx[off[b * NN + r] + p] = (u32)e;
}

// P = nodes*W1a, Q = nodes*W1b  (dense per-node GEMMs, bf16 out, row-major [node][h])
__global__ __launch_bounds__(256) void pq_kernel(
    const u16* __restrict__ nodesbf, const u16* __restrict__ wb,
    u16* __restrict__ pbuf, u16* __restrict__ qbuf) {
  const int t = threadIdx.x;
  const int lane = t & 63, wv = t >> 6, lg = lane >> 4, lr = lane & 15;
  const int sel = blockIdx.x >> 9;
  const int bb = blockIdx.x & 511;
  const int b = bb >> 8;
  const int m0 = (bb & 255) << 6;
  const u16* __restrict__ W = wb + (sel ? O_EW1B : O_EW1A);
  u16* __restrict__ outb = (sel ? qbuf : pbuf) + (size_t)b * NN * DN;
  const u16* __restrict__ nbf = nodesbf + (size_t)b * NN * DN;
  const int nb = wv * 64;

  f32x4 acc[4][4];
#pragma unroll
  for (int i = 0; i < 4; ++i)
#pragma unroll
    for (int j = 0; j < 4; ++j) acc[i][j] = (f32x4){0.f, 0.f, 0.f, 0.f};

#pragma unroll 2
  for (int kt = 0; kt < 8; ++kt) {
    const int k = kt * 32 + lg * 8;
    bf16x8 xf[4];
#pragma unroll
    for (int nf = 0; nf < 4; ++nf)
      xf[nf] = *(const bf16x8*)(W + (size_t)(nb + nf * 16 + lr) * 256 + k);
    bf16x8 yf[4];
#pragma unroll
    for (int ef = 0; ef < 4; ++ef)
      yf[ef] = *(const bf16x8*)(nbf + (size_t)(m0 + ef * 16 + lr) * 256 + k);
#pragma unroll
    for (int nf = 0; nf < 4; ++nf)
#pragma unroll
      for (int ef = 0; ef < 4; ++ef)
        acc[nf][ef] = __builtin_amdgcn_mfma_f32_16x16x32_bf16(
            xf[nf], yf[ef], acc[nf][ef], 0, 0, 0);
  }

#pragma unroll
  for (int nf = 0; nf < 4; ++nf)
#pragma unroll
    for (int ef = 0; ef < 4; ++ef) {
      int row = m0 + ef * 16 + lr;
      *(u64*)(outb + (size_t)row * 256 + nb + nf * 16 + lg * 4) = pack4bf(acc[nf][ef]);
    }
}

__global__ __launch_bounds__(256) void edge_kernel(
    const float* __restrict__ edges,
    const int* __restrict__ senders, const int* __restrict__ receivers,
    const float* __restrict__ eb1, const float* __restrict__ eb2,
    const u16* __restrict__ eW1cT, const u16* __restrict__ eW2T,
    const u16* __restrict__ pbuf, const u16* __restrict__ qbuf,
    float* __restrict__ out_edges) {
  // S: [64 e][256 h] bf16 (32KB, 16B-slot XOR swizzle) = P[r]+Q[s]
  // E: [64 e][128 k] bf16 (16KB, 16B-slot XOR swizzle) = edge feats
  // hT overlays S after epilogue-1 (per-wave byte-stripes are disjoint).
  __shared__ __align__(16) u16 smem[24576];
  u16* S = smem;
  u16* E = smem + 16384;
  u64* hT = (u64*)smem;

  const int t = threadIdx.x;
  const int lane = t & 63, wv = t >> 6, lg = lane >> 4, lr = lane & 15;
  const int b = blockIdx.x >> 11;
  const int e0 = (blockIdx.x << 6) & (NE - 1);
  const size_t bNE = (size_t)b * NE;
  const u16* __restrict__ Pb = pbuf + (size_t)b * NN * DN;
  const u16* __restrict__ Qb = qbuf + (size_t)b * NN * DN;

  // ---- stage S = P[recv] + Q[send]  (coalesced per row: 2 rows per wave-instr)
#pragma unroll
  for (int i = 0; i < 8; ++i) {
    int gi = t + 256 * i;              // [row 0..63][slot 0..31]
    int row = gi >> 5, slot = gi & 31;
    int ri = receivers[bNE + e0 + row];
    int si = senders[bNE + e0 + row];
    bf16x8 pv = *(const bf16x8*)(Pb + (size_t)ri * 256 + slot * 8);
    bf16x8 qv = *(const bf16x8*)(Qb + (size_t)si * 256 + slot * 8);
    bf16x8 sv;
#pragma unroll
    for (int j = 0; j < 8; ++j)
      sv[j] = (short)f2bf(bf2f((u16)pv[j]) + bf2f((u16)qv[j]));
    *(bf16x8*)(S + row * 256 + ((slot ^ (row & 7)) << 3)) = sv;
  }

  // ---- stage E = bf16(edges tile)
#pragma unroll
  for (int i = 0; i < 4; ++i) {
    int gi = t + 256 * i;              // [row 0..63][slot 0..15]
    int row = gi >> 4, slot = gi & 15;
    *(bf16x8*)(E + row * 128 + ((slot ^ (row & 7)) << 3)) =
        load8f_bf(edges + (bNE + e0 + row) * DE + slot * 8);
  }
  __syncthreads();

  const int nb = wv * 64;
  f32x4 acc1[4][4];
#pragma unroll
  for (int i = 0; i < 4; ++i)
#pragma unroll
    for (int j = 0; j < 4; ++j) acc1[i][j] = (f32x4){0.f, 0.f, 0.f, 0.f};

  // ---- R-GEMM: acc1 = W1c^T . E^T   (K = 128, weights 64KB L2-hot)
#pragma unroll
  for (int kt = 0; kt < 4; ++kt) {
    const int k = kt * 32 + lg * 8;
    const int slot = kt * 4 + lg;
    bf16x8 xf[4];
#pragma unroll
    for (int nf = 0; nf < 4; ++nf)
      xf[nf] = *(const bf16x8*)(eW1cT + (size_t)(nb + nf * 16 + lr) * 128 + k);
    bf16x8 yf[4];
#pragma unroll
    for (int ef = 0; ef < 4; ++ef) {
      int row = ef * 16 + lr;
      yf[ef] = *(const bf16x8*)(E + row * 128 + ((slot ^ (row & 7)) << 3));
    }
#pragma unroll
    for (int nf = 0; nf < 4; ++nf)
#pragma unroll
      for (int ef = 0; ef < 4; ++ef)
        acc1[nf][ef] = __builtin_amdgcn_mfma_f32_16x16x32_bf16(
            xf[nf], yf[ef], acc1[nf][ef], 0, 0, 0);
  }

  // ---- epilogue 1: h = relu(acc1 + S + b1) -> hT (read ALL S frags first)
  u64 sv64[4][4];
#pragma unroll
  for (int nf = 0; nf < 4; ++nf)
#pragma unroll
    for (int ef = 0; ef < 4; ++ef) {
      int row = ef * 16 + lr;
      int s16 = 8 * wv + nf * 2 + (lg >> 1);
      sv64[nf][ef] = *(const u64*)(S + row * 256 + ((s16 ^ (row & 7)) << 3) + ((lg & 1) << 2));
    }
#pragma unroll
  for (int nf = 0; nf < 4; ++nf) {
    f32x4 bias = *(const f32x4*)(eb1 + nb + nf * 16 + lg * 4);
#pragma unroll
    for (int ef = 0; ef < 4; ++ef) {
      u64 q = sv64[nf][ef];
      f32x4 v;
#pragma unroll
      for (int j = 0; j < 4; ++j) {
        float sj = bf2f((u16)(q >> (16 * j)));
        float x = acc1[nf][ef][j] + sj + bias[j];
        v[j] = x > 0.f ? x : 0.f;
      }
      int e = ef * 16 + lr;
      int s = 16 * wv + nf * 4 + lg;
      hT[e * 64 + (s ^ (e & 7))] = pack4bf(v);
    }
  }
  __syncthreads();

  // ---- GEMM2: edges_new^T = W2^T . h^T, K = 256 (weights 64KB L2-hot)
  f32x4 acc2[2][4];
#pragma unroll
  for (int i = 0; i < 2; ++i)
#pragma unroll
    for (int j = 0; j < 4; ++j) acc2[i][j] = (f32x4){0.f, 0.f, 0.f, 0.f};

#pragma unroll 2
  for (int kf = 0; kf < 8; ++kf) {
    bf16x8 x2[2];
#pragma unroll
    for (int of = 0; of < 2; ++of)
      x2[of] = *(const bf16x8*)(eW2T + (size_t)(32 * wv + of * 16 + lr) * 256 + kf * 32 + lg * 8);
    bf16x8 y2[4];
#pragma unroll
    for (int ef = 0; ef < 4; ++ef) {
      int e = ef * 16 + lr;
      int s0 = kf * 8 + lg * 2;
      union { u64 q[2]; bf16x8 v; } uu;
      uu.q[0] = hT[e * 64 + (s0 ^ (e & 7))];
      uu.q[1] = hT[e * 64 + ((s0 + 1) ^ (e & 7))];
      y2[ef] = uu.v;
    }
#pragma unroll
    for (int of = 0; of < 2; ++of)
#pragma unroll
      for (int ef = 0; ef < 4; ++ef)
        acc2[of][ef] = __builtin_amdgcn_mfma_f32_16x16x32_bf16(
            x2[of], y2[ef], acc2[of][ef], 0, 0, 0);
  }

  // ---- epilogue 2: residual edges_out (no atomics)
#pragma unroll
  for (int of = 0; of < 2; ++of) {
    const int obase = 32 * wv + of * 16 + lg * 4;
    f32x4 b2 = *(const f32x4*)(eb2 + obase);
#pragma unroll
    for (int ef = 0; ef < 4; ++ef) {
      f32x4 en = acc2[of][ef] + b2;
      size_t erow = bNE + e0 + ef * 16 + lr;
      f32x4 eold = *(const f32x4*)(edges + erow * DE + obase);
      *(f32x4*)(out_edges + erow * DE + obase) = eold + en;
    }
  }
}

// agg[n] = sum over CSR edge list of (edges_out - edges), f32 accum -> bf16.
// One wave per node; lane owns 2 of the 128 cols.
__global__ __launch_bounds__(256) void gather_kernel(
    const float* __restrict__ edges, const float* __restrict__ out_edges,
    const u32* __restrict__ cnt, const u32* __restrict__ off,
    const u32* __restrict__ eidx, u16* __restrict__ aggbf) {
  const int t = threadIdx.x;
  const int lane = t & 63, wv = t >> 6;
  const int g = blockIdx.x * 4 + wv;         // 0..32767 (b*NN+n)
  const int b = g >> 14;
  const size_t bNE = (size_t)b * NE;

  const u32 deg = cnt[g];
  const u32 base = off[g];
  float a0 = 0.f, a1 = 0.f;
#pragma unroll 2
  for (u32 i = 0; i < deg; ++i) {
    u32 e = eidx[base + i];
    const float* ro = out_edges + (bNE + e) * DE + lane * 2;
    const float* ri = edges + (bNE + e) * DE + lane * 2;
    f32x2 vo = *(const f32x2*)ro;
    f32x2 vi = *(const f32x2*)ri;
    a0 += vo[0] - vi[0];
    a1 += vo[1] - vi[1];
  }
  u32 w = (u32)f2bf(a0) | ((u32)f2bf(a1) << 16);
  *(u32*)(aggbf + (size_t)g * DE + lane * 2) = w;
}

// node MLP: 32-row tiles, 1024 blocks -> 4 blocks/CU for latency hiding
__global__ __launch_bounds__(256) void node_kernel(
    const float* __restrict__ nodes,
    const float* __restrict__ nb1v, const float* __restrict__ nb2v,
    const u16* __restrict__ nW1T, const u16* __restrict__ nW2T,
    const u16* __restrict__ nodesbf, const u16* __restrict__ aggbf,
    float* __restrict__ out_nodes) {
  __shared__ __align__(16) u64 hT[2048];  // [32 m][64 slots]

  const int t = threadIdx.x;
  const int lane = t & 63, wv = t >> 6, lg = lane >> 4, lr = lane & 15;
  const int b = blockIdx.x >> 9;
  const int m0 = (blockIdx.x & 511) << 5;

  const u16* __restrict__ nbf = nodesbf + (size_t)b * NN * DN;
  const u16* __restrict__ abf = aggbf + (size_t)b * NN * DE;
  const int nb = wv * 64;

  f32x4 acc1[4][2];
#pragma unroll
  for (int i = 0; i < 4; ++i)
#pragma unroll
    for (int j = 0; j < 2; ++j) acc1[i][j] = (f32x4){0.f, 0.f, 0.f, 0.f};

  // ---- GEMM1: K = 384 (agg 0..127 | nodes 128..383)
#pragma unroll 2
  for (int kt = 0; kt < 12; ++kt) {
    const int k = kt * 32 + lg * 8;
    bf16x8 xf[4];
#pragma unroll
    for (int nf = 0; nf < 4; ++nf)
      xf[nf] = *(const bf16x8*)(nW1T + (size_t)(nb + nf * 16 + lr) * 384 + k);
    bf16x8 yf[2];
    if (kt < 4) {
#pragma unroll
      for (int ef = 0; ef < 2; ++ef)
        yf[ef] = *(const bf16x8*)(abf + (size_t)(m0 + ef * 16 + lr) * DE + k);
    } else {
#pragma unroll
      for (int ef = 0; ef < 2; ++ef)
        yf[ef] = *(const bf16x8*)(nbf + (size_t)(m0 + ef * 16 + lr) * DN + (k - 128));
    }
#pragma unroll
    for (int nf = 0; nf < 4; ++nf)
#pragma unroll
      for (int ef = 0; ef < 2; ++ef)
        acc1[nf][ef] = __builtin_amdgcn_mfma_f32_16x16x32_bf16(
            xf[nf], yf[ef], acc1[nf][ef], 0, 0, 0);
  }

  // ---- epilogue 1
#pragma unroll
  for (int nf = 0; nf < 4; ++nf) {
    f32x4 bias = *(const f32x4*)(nb1v + nb + nf * 16 + lg * 4);
#pragma unroll
    for (int ef = 0; ef < 2; ++ef) {
      f32x4 v = acc1[nf][ef] + bias;
#pragma unroll
      for (int j = 0; j < 4; ++j) v[j] = v[j] > 0.f ? v[j] : 0.f;
      int e = ef * 16 + lr;
      int s = 16 * wv + nf * 4 + lg;
      hT[e * 64 + (s ^ (e & 7))] = pack4bf(v);
    }
  }
  __syncthreads();

  // ---- GEMM2: K = 256
  f32x4 acc2[4][2];
#pragma unroll
  for (int i = 0; i < 4; ++i)
#pragma unroll
    for (int j = 0; j < 2; ++j) acc2[i][j] = (f32x4){0.f, 0.f, 0.f, 0.f};

#pragma unroll 2
  for (int kf = 0; kf < 8; ++kf) {
    bf16x8 x2[4];
#pragma unroll
    for (int of = 0; of < 4; ++of)
      x2[of] = *(const bf16x8*)(nW2T + (size_t)(64 * wv + of * 16 + lr) * 256 + kf * 32 + lg * 8);
    bf16x8 y2[2];
#pragma unroll
    for (int ef = 0; ef < 2; ++ef) {
      int e = ef * 16 + lr;
      int s0 = kf * 8 + lg * 2;
      union { u64 q[2]; bf16x8 v; } uu;
      uu.q[0] = hT[e * 64 + (s0 ^ (e & 7))];
      uu.q[1] = hT[e * 64 + ((s0 + 1) ^ (e & 7))];
      y2[ef] = uu.v;
    }
#pragma unroll
    for (int of = 0; of < 4; ++of)
#pragma unroll
      for (int ef = 0; ef < 2; ++ef)
        acc2[of][ef] = __builtin_amdgcn_mfma_f32_16x16x32_bf16(
            x2[of], y2[ef], acc2[of][ef], 0, 0, 0);
  }

  // ---- epilogue 2: bias + residual
#pragma unroll
  for (int of = 0; of < 4; ++of) {
    const int obase = 64 * wv + of * 16 + lg * 4;
    f32x4 b2 = *(const f32x4*)(nb2v + obase);
#pragma unroll
    for (int ef = 0; ef < 2; ++ef) {
      f32x4 nn = acc2[of][ef] + b2;
      size_t mrow = (size_t)b * NN + m0 + ef * 16 + lr;
      f32x4 nold = *(const f32x4*)(nodes + mrow * DN + obase);
      *(f32x4*)(out_nodes + mrow * DN + obase) = nold + nn;
    }
  }
}

extern "C" void kernel_launch(void* const* d_in, const int* in_sizes, int n_in,
                              void* d_out, int out_size, void* d_ws, size_t ws_size,
                              hipStream_t stream) {
  const float* nodes = (const float*)d_in[0];
  const float* edges = (const float*)d_in[1];
  const int* senders = (const int*)d_in[2];
  const int* receivers = (const int*)d_in[3];
  const float* eW1 = (const float*)d_in[4];
  const float* eb1 = (const float*)d_in[5];
  const float* eW2 = (const float*)d_in[6];
  const float* eb2 = (const float*)d_in[7];
  const float* nW1 = (const float*)d_in[8];
  const float* nb1 = (const float*)d_in[9];
  const float* nW2 = (const float*)d_in[10];
  const float* nb2 = (const float*)d_in[11];

  char* ws = (char*)d_ws;
  u16* wb = (u16*)(ws + WS_WB);
  u16* nodesbf = (u16*)(ws + WS_NODESBF);
  u32* cnt = (u32*)(ws + WS_CNT);
  u32* off = (u32*)(ws + WS_OFF);
  u32* cur = (u32*)(ws + WS_CUR);
  u32* eidx = (u32*)(ws + WS_EIDX);
  u16* aggbf = (u16*)(ws + WS_AGGBF);
  u16* pbuf = (u16*)(ws + WS_PBUF);
  u16* qbuf = (u16*)(ws + WS_QBUF);
  float* out = (float*)d_out;
  float* out_edges = out + (size_t)BATCH * NN * DN;

  hipMemsetAsync(cnt, 0, 32768 * sizeof(u32), stream);
  hipMemsetAsync(cur, 0, 32768 * sizeof(u32), stream);
  prep_weights<<<1408, 256, 0, stream>>>(eW1, eW2, nW1, nW2, wb);
  prep_nodes<<<2048, 256, 0, stream>>>(nodes, (u64*)nodesbf);
  pq_kernel<<<1024, 256, 0, stream>>>(nodesbf, wb, pbuf, qbuf);
  hist_kernel<<<1024, 256, 0, stream>>>(receivers, cnt);
  scan_kernel<<<1, 1024, 0, stream>>>(cnt, off);
  fill_kernel<<<1024, 256, 0, stream>>>(receivers, off, cur, eidx);
  edge_kernel<<<4096, 256, 0, stream>>>(edges, senders, receivers, eb1, eb2,
                                        wb + O_EW1C, wb + O_EW2T, pbuf, qbuf,
                                        out_edges);
  gather_kernel<<<8192, 256, 0, stream>>>(edges, out_edges, cnt, off, eidx, aggbf);
  node_kernel<<<1024, 256, 0, stream>>>(nodes, nb1, nb2, wb + O_NW1T, wb + O_NW2T,
                                        nodesbf, aggbf, out);
  (void)in_sizes; (void)n_in; (void)out_size; (void)ws_size;
}

// Round 7
// 572.893 us; speedup vs baseline: 1.6363x; 1.0183x over previous
//
#include <hip/hip_runtime.h>
#include <hip/hip_bf16.h>

// InteractionNetworkLayer on MI355X — round 6 resubmit (prior bench hit
// GPUAcquisitionTimeout): async edge staging + bucket CSR + merged PQ.
//
// Edge phases: {issue P gathers via global_load_lds (linear dest, inverse-
// swizzled global src), issue Q frag loads to regs, stage E} -> lgkm barrier ->
// R-GEMM (covers gather latency) -> vmcnt barrier -> epilogue1 (P from LDS,
// Q from regs, relu -> hT overlaying P) -> lgkm barrier -> GEMM2 -> residual.
// CSR: one-pass capacity-64 buckets (no scan). PQ: one kernel, shared loads.

typedef __attribute__((ext_vector_type(8))) short bf16x8;
typedef __attribute__((ext_vector_type(4))) float f32x4;
typedef __attribute__((ext_vector_type(2))) float f32x2;
typedef unsigned long long u64;
typedef unsigned short u16;
typedef unsigned int u32;

#define BATCH 2
#define NN 16384
#define NE 131072
#define DN 256
#define DE 128

#if defined(__has_builtin)
#if __has_builtin(__builtin_amdgcn_global_load_lds)
#define USE_GLOAD_LDS 1
#endif
#endif

// u16-unit offsets inside the weight block
#define O_EW1A 0        // [256h][256k]   recv block of eW1
#define O_EW1B 65536    // [256h][256k]   send block
#define O_EW1C 131072   // [256h][128k]   edge-feat block
#define O_EW2T 163840   // [128o][256k]
#define O_NW1T 196608   // [256h][384k]
#define O_NW2T 294912   // [256o][256k]

// ws byte offsets
#define WS_WB      0u
#define WS_NODESBF 720896u    // 2*16384*256 bf16 = 16777216 B
#define WS_CNT     17498112u  // 32768 u32 = 131072 B
#define WS_EIDX    17629184u  // 32768*64 u32 = 8388608 B
#define WS_AGGBF   34275328u  // 2*16384*128 bf16 = 8388608 B
#define WS_PBUF    42663936u  // 2*16384*256 bf16 = 16777216 B
#define WS_QBUF    59441152u  // 2*16384*256 bf16 = 16777216 B
// end: 76218368 B

__device__ inline u16 f2bf(float f) {
  u32 u = __builtin_bit_cast(u32, f);
  u32 r = u + 0x7FFFu + ((u >> 16) & 1u);
  return (u16)(r >> 16);
}

__device__ inline float bf2f(u16 h) {
  u32 u = ((u32)h) << 16;
  return __builtin_bit_cast(float, u);
}

__device__ inline u64 pack4bf(f32x4 v) {
  return (u64)f2bf(v[0]) | ((u64)f2bf(v[1]) << 16) |
         ((u64)f2bf(v[2]) << 32) | ((u64)f2bf(v[3]) << 48);
}

__device__ inline bf16x8 load8f_bf(const float* __restrict__ p) {
  f32x4 a = *(const f32x4*)p;
  f32x4 c = *(const f32x4*)(p + 4);
  bf16x8 r;
  r[0] = (short)f2bf(a[0]); r[1] = (short)f2bf(a[1]);
  r[2] = (short)f2bf(a[2]); r[3] = (short)f2bf(a[3]);
  r[4] = (short)f2bf(c[0]); r[5] = (short)f2bf(c[1]);
  r[6] = (short)f2bf(c[2]); r[7] = (short)f2bf(c[3]);
  return r;
}

__global__ void prep_weights(const float* __restrict__ eW1, const float* __restrict__ eW2,
                             const float* __restrict__ nW1, const float* __restrict__ nW2,
                             u16* __restrict__ wb) {
  int o = blockIdx.x * 256 + threadIdx.x;
  if (o < 65536) {                        // eW1aT[h][k] (recv rows of eW1)
    int h = o >> 8, k = o & 255;
    wb[O_EW1A + o] = f2bf(eW1[k * 256 + h]);
  } else if (o < 131072) {                // eW1bT[h][k], rows 256..511
    int o2 = o - 65536; int h = o2 >> 8, k = o2 & 255;
    wb[O_EW1B + o2] = f2bf(eW1[(256 + k) * 256 + h]);
  } else if (o < 163840) {                // eW1cT[h][k], rows 512..639
    int o3 = o - 131072; int h = o3 >> 7, k = o3 & 127;
    wb[O_EW1C + o3] = f2bf(eW1[(512 + k) * 256 + h]);
  } else if (o < 196608) {                // eW2T[o][k]
    int o4 = o - 163840; int n = o4 >> 8, k = o4 & 255;
    wb[O_EW2T + o4] = f2bf(eW2[k * 128 + n]);
  } else if (o < 294912) {                // nW1T[h][k], k<384
    int o5 = o - 196608; int n = o5 / 384, k = o5 % 384;
    wb[O_NW1T + o5] = f2bf(nW1[k * 256 + n]);
  } else if (o < 360448) {                // nW2T[o][k]
    int o6 = o - 294912; int n = o6 >> 8, k = o6 & 255;
    wb[O_NW2T + o6] = f2bf(nW2[k * 256 + n]);
  }
}

__global__ void prep_nodes(const float* __restrict__ nodes, u64* __restrict__ nbf) {
  const size_t total = (size_t)BATCH * NN * DN / 4;
  for (size_t i = (size_t)blockIdx.x * 256 + threadIdx.x; i < total;
       i += (size_t)gridDim.x * 256) {
    f32x4 v = ((const f32x4*)nodes)[i];
    nbf[i] = pack4bf(v);
  }
}

// One-pass bucket CSR: cnt[g] = degree, eidx[g][0..63] = edge ids (any order).
__global__ void fill_kernel(const int* __restrict__ receivers,
                            u32* __restrict__ cnt, u32* __restrict__ eidx) {
  int i = blockIdx.x * 256 + threadIdx.x;       // 262144 exact
  int b = i >> 17, e = i & (NE - 1);
  int r = receivers[(size_t)b * NE + e];
  int g = b * NN + r;
  u32 p = atomicAdd(&cnt[g], 1u);
  if (p < 64) eidx[(size_t)g * 64 + p] = (u32)e;
}

// P = nodes*W1a and Q = nodes*W1b in one pass (shared node-fragment loads).
__global__ __launch_bounds__(256) void pq_kernel(
    const u16* __restrict__ nodesbf, const u16* __restrict__ wb,
    u16* __restrict__ pbuf, u16* __restrict__ qbuf) {
  const int t = threadIdx.x;
  const int lane = t & 63, wv = t >> 6, lg = lane >> 4, lr = lane & 15;
  const int b = blockIdx.x >> 9;
  const int m0 = (blockIdx.x & 511) << 5;     // 32-row tiles
  const u16* __restrict__ Wa = wb + O_EW1A;
  const u16* __restrict__ Wb2 = wb + O_EW1B;
  const u16* __restrict__ nbf = nodesbf + (size_t)b * NN * DN;
  u16* __restrict__ pb = pbuf + (size_t)b * NN * DN;
  u16* __restrict__ qb = qbuf + (size_t)b * NN * DN;
  const int nb = wv * 64;

  f32x4 ap[4][2], aq[4][2];
#pragma unroll
  for (int i = 0; i < 4; ++i)
#pragma unroll
    for (int j = 0; j < 2; ++j) {
      ap[i][j] = (f32x4){0.f, 0.f, 0.f, 0.f};
      aq[i][j] = (f32x4){0.f, 0.f, 0.f, 0.f};
    }

#pragma unroll 2
  for (int kt = 0; kt < 8; ++kt) {
    const int k = kt * 32 + lg * 8;
    bf16x8 yf[2];
#pragma unroll
    for (int ef = 0; ef < 2; ++ef)
      yf[ef] = *(const bf16x8*)(nbf + (size_t)(m0 + ef * 16 + lr) * 256 + k);
    bf16x8 xa[4], xb[4];
#pragma unroll
    for (int nf = 0; nf < 4; ++nf) {
      xa[nf] = *(const bf16x8*)(Wa + (size_t)(nb + nf * 16 + lr) * 256 + k);
      xb[nf] = *(const bf16x8*)(Wb2 + (size_t)(nb + nf * 16 + lr) * 256 + k);
    }
#pragma unroll
    for (int nf = 0; nf < 4; ++nf)
#pragma unroll
      for (int ef = 0; ef < 2; ++ef) {
        ap[nf][ef] = __builtin_amdgcn_mfma_f32_16x16x32_bf16(xa[nf], yf[ef], ap[nf][ef], 0, 0, 0);
        aq[nf][ef] = __builtin_amdgcn_mfma_f32_16x16x32_bf16(xb[nf], yf[ef], aq[nf][ef], 0, 0, 0);
      }
  }

#pragma unroll
  for (int nf = 0; nf < 4; ++nf)
#pragma unroll
    for (int ef = 0; ef < 2; ++ef) {
      int row = m0 + ef * 16 + lr;
      *(u64*)(pb + (size_t)row * 256 + nb + nf * 16 + lg * 4) = pack4bf(ap[nf][ef]);
      *(u64*)(qb + (size_t)row * 256 + nb + nf * 16 + lg * 4) = pack4bf(aq[nf][ef]);
    }
}

__global__ __launch_bounds__(256) void edge_kernel(
    const float* __restrict__ edges,
    const int* __restrict__ senders, const int* __restrict__ receivers,
    const float* __restrict__ eb1, const float* __restrict__ eb2,
    const u16* __restrict__ eW1cT, const u16* __restrict__ eW2T,
    const u16* __restrict__ pbuf, const u16* __restrict__ qbuf,
    float* __restrict__ out_edges) {
  // LDS 48KB: P [64 rows][256 u16] @0 (linear dest for DMA; 16B slot s holds
  // logical slot s^(row&7) via inverse-swizzled global src); E [64][128] u16
  // @16384. hT [64][64] u64 overlays P (per-wave 128B stripes, read-then-write).
  __shared__ __align__(16) u16 smem[24576];
  u16* E = smem + 16384;
  u64* hT = (u64*)smem;

  const int t = threadIdx.x;
  const int lane = t & 63, wv = t >> 6, lg = lane >> 4, lr = lane & 15;
  const int b = blockIdx.x >> 11;
  const int e0 = (blockIdx.x << 6) & (NE - 1);
  const size_t bNE = (size_t)b * NE;
  const u16* __restrict__ Pb = pbuf + (size_t)b * NN * DN;
  const u16* __restrict__ Qb = qbuf + (size_t)b * NN * DN;
  const int nb = wv * 64;

  // ---- issue Q fragment loads early (regs, consumed in epilogue 1)
  int s_ef[4];
#pragma unroll
  for (int ef = 0; ef < 4; ++ef) s_ef[ef] = senders[bNE + e0 + ef * 16 + lr];
  u64 q64[4][4];
#pragma unroll
  for (int nf = 0; nf < 4; ++nf)
#pragma unroll
    for (int ef = 0; ef < 4; ++ef)
      q64[nf][ef] = *(const u64*)(Qb + (size_t)s_ef[ef] * 256 + nb + nf * 16 + lg * 4);

  // ---- issue P row gathers: async DMA to LDS (2 rows / instr / wave)
#pragma unroll
  for (int j = 0; j < 8; ++j) {
    const int ii = wv * 8 + j;                 // 0..31
    const int row = 2 * ii + (lane >> 5);
    const int ri = receivers[bNE + e0 + row];
    const int ssl = (lane & 31) ^ (row & 7);   // inverse-swizzled source slot
    const u16* src = Pb + (size_t)ri * 256 + ssl * 8;
#ifdef USE_GLOAD_LDS
    __builtin_amdgcn_global_load_lds(
        (const __attribute__((address_space(1))) void*)src,
        (__attribute__((address_space(3))) void*)((char*)smem + ii * 1024),
        16, 0, 0);
#else
    *(bf16x8*)((char*)smem + row * 512 + (lane & 31) * 16) = *(const bf16x8*)src;
#endif
  }

  // ---- stage E = bf16(edges tile)
#pragma unroll
  for (int i = 0; i < 4; ++i) {
    int gi = t + 256 * i;
    int row = gi >> 4, slot = gi & 15;
    *(bf16x8*)(E + row * 128 + ((slot ^ (row & 7)) << 3)) =
        load8f_bf(edges + (bNE + e0 + row) * DE + slot * 8);
  }
  asm volatile("s_waitcnt lgkmcnt(0)" ::: "memory");
  __builtin_amdgcn_s_barrier();               // E ready; P DMA still in flight

  // ---- R-GEMM: acc1 = W1c^T . E^T   (K = 128)
  f32x4 acc1[4][4];
#pragma unroll
  for (int i = 0; i < 4; ++i)
#pragma unroll
    for (int j = 0; j < 4; ++j) acc1[i][j] = (f32x4){0.f, 0.f, 0.f, 0.f};

#pragma unroll
  for (int kt = 0; kt < 4; ++kt) {
    const int k = kt * 32 + lg * 8;
    const int slot = kt * 4 + lg;
    bf16x8 xf[4];
#pragma unroll
    for (int nf = 0; nf < 4; ++nf)
      xf[nf] = *(const bf16x8*)(eW1cT + (size_t)(nb + nf * 16 + lr) * 128 + k);
    bf16x8 yf[4];
#pragma unroll
    for (int ef = 0; ef < 4; ++ef) {
      int row = ef * 16 + lr;
      yf[ef] = *(const bf16x8*)(E + row * 128 + ((slot ^ (row & 7)) << 3));
    }
#pragma unroll
    for (int nf = 0; nf < 4; ++nf)
#pragma unroll
      for (int ef = 0; ef < 4; ++ef)
        acc1[nf][ef] = __builtin_amdgcn_mfma_f32_16x16x32_bf16(
            xf[nf], yf[ef], acc1[nf][ef], 0, 0, 0);
  }

  asm volatile("s_waitcnt vmcnt(0)" ::: "memory");
  __builtin_amdgcn_s_barrier();               // P rows in LDS everywhere

  // ---- epilogue 1: h = relu(acc1 + P + Q + b1) -> hT (read all P first)
  u64 p64[4][4];
#pragma unroll
  for (int nf = 0; nf < 4; ++nf)
#pragma unroll
    for (int ef = 0; ef < 4; ++ef) {
      int e = ef * 16 + lr;
      int s16 = 8 * wv + nf * 2 + (lg >> 1);
      p64[nf][ef] = *(const u64*)(smem + e * 256 + ((s16 ^ (e & 7)) << 3) + ((lg & 1) << 2));
    }
#pragma unroll
  for (int nf = 0; nf < 4; ++nf) {
    f32x4 bias = *(const f32x4*)(eb1 + nb + nf * 16 + lg * 4);
#pragma unroll
    for (int ef = 0; ef < 4; ++ef) {
      u64 pq = p64[nf][ef], qq = q64[nf][ef];
      f32x4 v;
#pragma unroll
      for (int j = 0; j < 4; ++j) {
        float x = acc1[nf][ef][j] + bf2f((u16)(pq >> (16 * j))) +
                  bf2f((u16)(qq >> (16 * j))) + bias[j];
        v[j] = x > 0.f ? x : 0.f;
      }
      int e = ef * 16 + lr;
      int s = 16 * wv + nf * 4 + lg;
      hT[e * 64 + (s ^ (e & 7))] = pack4bf(v);
    }
  }
  asm volatile("s_waitcnt lgkmcnt(0)" ::: "memory");
  __builtin_amdgcn_s_barrier();               // hT visible

  // ---- GEMM2: edges_new^T = W2^T . h^T, K = 256
  f32x4 acc2[2][4];
#pragma unroll
  for (int i = 0; i < 2; ++i)
#pragma unroll
    for (int j = 0; j < 4; ++j) acc2[i][j] = (f32x4){0.f, 0.f, 0.f, 0.f};

#pragma unroll 2
  for (int kf = 0; kf < 8; ++kf) {
    bf16x8 x2[2];
#pragma unroll
    for (int of = 0; of < 2; ++of)
      x2[of] = *(const bf16x8*)(eW2T + (size_t)(32 * wv + of * 16 + lr) * 256 + kf * 32 + lg * 8);
    bf16x8 y2[4];
#pragma unroll
    for (int ef = 0; ef < 4; ++ef) {
      int e = ef * 16 + lr;
      int s0 = kf * 8 + lg * 2;
      union { u64 q[2]; bf16x8 v; } uu;
      uu.q[0] = hT[e * 64 + (s0 ^ (e & 7))];
      uu.q[1] = hT[e * 64 + ((s0 + 1) ^ (e & 7))];
      y2[ef] = uu.v;
    }
#pragma unroll
    for (int of = 0; of < 2; ++of)
#pragma unroll
      for (int ef = 0; ef < 4; ++ef)
        acc2[of][ef] = __builtin_amdgcn_mfma_f32_16x16x32_bf16(
            x2[of], y2[ef], acc2[of][ef], 0, 0, 0);
  }

  // ---- epilogue 2: residual edges_out
#pragma unroll
  for (int of = 0; of < 2; ++of) {
    const int obase = 32 * wv + of * 16 + lg * 4;
    f32x4 b2 = *(const f32x4*)(eb2 + obase);
#pragma unroll
    for (int ef = 0; ef < 4; ++ef) {
      f32x4 en = acc2[of][ef] + b2;
      size_t erow = bNE + e0 + ef * 16 + lr;
      f32x4 eold = *(const f32x4*)(edges + erow * DE + obase);
      *(f32x4*)(out_edges + erow * DE + obase) = eold + en;
    }
  }
}

// agg[n] = sum over bucket list of (edges_out - edges), f32 accum -> bf16.
__global__ __launch_bounds__(256) void gather_kernel(
    const float* __restrict__ edges, const float* __restrict__ out_edges,
    const u32* __restrict__ cnt, const u32* __restrict__ eidx,
    u16* __restrict__ aggbf) {
  const int t = threadIdx.x;
  const int lane = t & 63, wv = t >> 6;
  const int g = blockIdx.x * 4 + wv;          // b*NN + n
  const int b = g >> 14;
  const size_t bNE = (size_t)b * NE;

  u32 deg = cnt[g];
  if (deg > 64) deg = 64;
  const u32* __restrict__ el = eidx + (size_t)g * 64;
  float a0 = 0.f, a1 = 0.f;
#pragma unroll 2
  for (u32 i = 0; i < deg; ++i) {
    u32 e = el[i];
    f32x2 vo = *(const f32x2*)(out_edges + (bNE + e) * DE + lane * 2);
    f32x2 vi = *(const f32x2*)(edges + (bNE + e) * DE + lane * 2);
    a0 += vo[0] - vi[0];
    a1 += vo[1] - vi[1];
  }
  u32 w = (u32)f2bf(a0) | ((u32)f2bf(a1) << 16);
  *(u32*)(aggbf + (size_t)g * DE + lane * 2) = w;
}

// node MLP: 32-row tiles, 1024 blocks
__global__ __launch_bounds__(256) void node_kernel(
    const float* __restrict__ nodes,
    const float* __restrict__ nb1v, const float* __restrict__ nb2v,
    const u16* __restrict__ nW1T, const u16* __restrict__ nW2T,
    const u16* __restrict__ nodesbf, const u16* __restrict__ aggbf,
    float* __restrict__ out_nodes) {
  __shared__ __align__(16) u64 hT[2048];

  const int t = threadIdx.x;
  const int lane = t & 63, wv = t >> 6, lg = lane >> 4, lr = lane & 15;
  const int b = blockIdx.x >> 9;
  const int m0 = (blockIdx.x & 511) << 5;

  const u16* __restrict__ nbf = nodesbf + (size_t)b * NN * DN;
  const u16* __restrict__ abf = aggbf + (size_t)b * NN * DE;
  const int nb = wv * 64;

  f32x4 acc1[4][2];
#pragma unroll
  for (int i = 0; i < 4; ++i)
#pragma unroll
    for (int j = 0; j < 2; ++j) acc1[i][j] = (f32x4){0.f, 0.f, 0.f, 0.f};

#pragma unroll 2
  for (int kt = 0; kt < 12; ++kt) {
    const int k = kt * 32 + lg * 8;
    bf16x8 xf[4];
#pragma unroll
    for (int nf = 0; nf < 4; ++nf)
      xf[nf] = *(const bf16x8*)(nW1T + (size_t)(nb + nf * 16 + lr) * 384 + k);
    bf16x8 yf[2];
    if (kt < 4) {
#pragma unroll
      for (int ef = 0; ef < 2; ++ef)
        yf[ef] = *(const bf16x8*)(abf + (size_t)(m0 + ef * 16 + lr) * DE + k);
    } else {
#pragma unroll
      for (int ef = 0; ef < 2; ++ef)
        yf[ef] = *(const bf16x8*)(nbf + (size_t)(m0 + ef * 16 + lr) * DN + (k - 128));
    }
#pragma unroll
    for (int nf = 0; nf < 4; ++nf)
#pragma unroll
      for (int ef = 0; ef < 2; ++ef)
        acc1[nf][ef] = __builtin_amdgcn_mfma_f32_16x16x32_bf16(
            xf[nf], yf[ef], acc1[nf][ef], 0, 0, 0);
  }

#pragma unroll
  for (int nf = 0; nf < 4; ++nf) {
    f32x4 bias = *(const f32x4*)(nb1v + nb + nf * 16 + lg * 4);
#pragma unroll
    for (int ef = 0; ef < 2; ++ef) {
      f32x4 v = acc1[nf][ef] + bias;
#pragma unroll
      for (int j = 0; j < 4; ++j) v[j] = v[j] > 0.f ? v[j] : 0.f;
      int e = ef * 16 + lr;
      int s = 16 * wv + nf * 4 + lg;
      hT[e * 64 + (s ^ (e & 7))] = pack4bf(v);
    }
  }
  __syncthreads();

  f32x4 acc2[4][2];
#pragma unroll
  for (int i = 0; i < 4; ++i)
#pragma unroll
    for (int j = 0; j < 2; ++j) acc2[i][j] = (f32x4){0.f, 0.f, 0.f, 0.f};

#pragma unroll 2
  for (int kf = 0; kf < 8; ++kf) {
    bf16x8 x2[4];
#pragma unroll
    for (int of = 0; of < 4; ++of)
      x2[of] = *(const bf16x8*)(nW2T + (size_t)(64 * wv + of * 16 + lr) * 256 + kf * 32 + lg * 8);
    bf16x8 y2[2];
#pragma unroll
    for (int ef = 0; ef < 2; ++ef) {
      int e = ef * 16 + lr;
      int s0 = kf * 8 + lg * 2;
      union { u64 q[2]; bf16x8 v; } uu;
      uu.q[0] = hT[e * 64 + (s0 ^ (e & 7))];
      uu.q[1] = hT[e * 64 + ((s0 + 1) ^ (e & 7))];
      y2[ef] = uu.v;
    }
#pragma unroll
    for (int of = 0; of < 4; ++of)
#pragma unroll
      for (int ef = 0; ef < 2; ++ef)
        acc2[of][ef] = __builtin_amdgcn_mfma_f32_16x16x32_bf16(
            x2[of], y2[ef], acc2[of][ef], 0, 0, 0);
  }

#pragma unroll
  for (int of = 0; of < 4; ++of) {
    const int obase = 64 * wv + of * 16 + lg * 4;
    f32x4 b2 = *(const f32x4*)(nb2v + obase);
#pragma unroll
    for (int ef = 0; ef < 2; ++ef) {
      f32x4 nn = acc2[of][ef] + b2;
      size_t mrow = (size_t)b * NN + m0 + ef * 16 + lr;
      f32x4 nold = *(const f32x4*)(nodes + mrow * DN + obase);
      *(f32x4*)(out_nodes + mrow * DN + obase) = nold + nn;
    }
  }
}

extern "C" void kernel_launch(void* const* d_in, const int* in_sizes, int n_in,
                              void* d_out, int out_size, void* d_ws, size_t ws_size,
                              hipStream_t stream) {
  const float* nodes = (const float*)d_in[0];
  const float* edges = (const float*)d_in[1];
  const int* senders = (const int*)d_in[2];
  const int* receivers = (const int*)d_in[3];
  const float* eW1 = (const float*)d_in[4];
  const float* eb1 = (const float*)d_in[5];
  const float* eW2 = (const float*)d_in[6];
  const float* eb2 = (const float*)d_in[7];
  const float* nW1 = (const float*)d_in[8];
  const float* nb1 = (const float*)d_in[9];
  const float* nW2 = (const float*)d_in[10];
  const float* nb2 = (const float*)d_in[11];

  char* ws = (char*)d_ws;
  u16* wb = (u16*)(ws + WS_WB);
  u16* nodesbf = (u16*)(ws + WS_NODESBF);
  u32* cnt = (u32*)(ws + WS_CNT);
  u32* eidx = (u32*)(ws + WS_EIDX);
  u16* aggbf = (u16*)(ws + WS_AGGBF);
  u16* pbuf = (u16*)(ws + WS_PBUF);
  u16* qbuf = (u16*)(ws + WS_QBUF);
  float* out = (float*)d_out;
  float* out_edges = out + (size_t)BATCH * NN * DN;

  hipMemsetAsync(cnt, 0, 32768 * sizeof(u32), stream);
  prep_weights<<<1408, 256, 0, stream>>>(eW1, eW2, nW1, nW2, wb);
  prep_nodes<<<2048, 256, 0, stream>>>(nodes, (u64*)nodesbf);
  pq_kernel<<<1024, 256, 0, stream>>>(nodesbf, wb, pbuf, qbuf);
  fill_kernel<<<1024, 256, 0, stream>>>(receivers, cnt, eidx);
  edge_kernel<<<4096, 256, 0, stream>>>(edges, senders, receivers, eb1, eb2,
                                        wb + O_EW1C, wb + O_EW2T, pbuf, qbuf,
                                        out_edges);
  gather_kernel<<<8192, 256, 0, stream>>>(edges, out_edges, cnt, eidx, aggbf);
  node_kernel<<<1024, 256, 0, stream>>>(nodes, nb1, nb2, wb + O_NW1T, wb + O_NW2T,
                                        nodesbf, aggbf, out);
  (void)in_sizes; (void)n_in; (void)out_size; (void)ws_size;
}